// Round 8
// baseline (393.137 us; speedup 1.0000x reference)
//
#include <hip/hip_runtime.h>
#include <hip/hip_fp8.h>
#include <stdint.h>

typedef unsigned short u16;
typedef unsigned char u8;
typedef __bf16 bf16x8 __attribute__((ext_vector_type(8)));
typedef float f32x4 __attribute__((ext_vector_type(4)));

__device__ __forceinline__ u16 f2bf(float f) {
  union { float f; unsigned u; } v; v.f = f;
  return (u16)((v.u + 0x7FFFu + ((v.u >> 16) & 1u)) >> 16);
}
__device__ __forceinline__ u8 f2f8(float f) {
  __hip_fp8_e4m3 h(f);
  return (u8)h.__x;
}

// async 16B global -> LDS (wave-uniform LDS base; HW writes base + lane*16)
__device__ __forceinline__ void gld_lds16(const void* g, void* l) {
  uint32_t lo = (uint32_t)(uintptr_t)l;
  lo = __builtin_amdgcn_readfirstlane(lo);
  auto* lp = (__attribute__((address_space(3))) uint32_t*)(uintptr_t)lo;
  auto* gp = (const __attribute__((address_space(1))) uint32_t*)(uintptr_t)g;
  __builtin_amdgcn_global_load_lds(gp, lp, 16, 0, 0);
}

// clobber-free barrier, fenced so no memory op crosses at schedule time.
__device__ __forceinline__ void bar() {
  __builtin_amdgcn_sched_barrier(0);
  __builtin_amdgcn_s_barrier();
  __builtin_amdgcn_sched_barrier(0);
}

// ---------------- weight fp32 -> bf16 ----------------
__global__ __launch_bounds__(256) void cvt_weights(
    const float* __restrict__ wq, const float* __restrict__ wp,
    u16* __restrict__ oq, u16* __restrict__ op) {
  int i = blockIdx.x * 256 + threadIdx.x;
  if (i < 1536 * 512) oq[i] = f2bf(wq[i]);
  if (i < 512 * 512)  op[i] = f2bf(wp[i]);
}

// ---------------- group norm stats ----------------
__global__ __launch_bounds__(256) void gn_stats(const float* __restrict__ x,
                                                float* __restrict__ stats) {
  int bg = blockIdx.x;  // 0..127
  const float* p = x + (size_t)bg * 65536;
  float s = 0.f, sq = 0.f;
  for (int i = threadIdx.x * 4; i < 65536; i += 1024) {
    float4 v = *(const float4*)(p + i);
    s += v.x + v.y + v.z + v.w;
    sq += v.x * v.x + v.y * v.y + v.z * v.z + v.w * v.w;
  }
  int lane = threadIdx.x & 63, w = threadIdx.x >> 6;
  for (int off = 32; off; off >>= 1) {
    s += __shfl_down(s, off);
    sq += __shfl_down(sq, off);
  }
  __shared__ float ls[4], lq[4];
  if (lane == 0) { ls[w] = s; lq[w] = sq; }
  __syncthreads();
  if (threadIdx.x == 0) {
    float S = ls[0] + ls[1] + ls[2] + ls[3];
    float Q = lq[0] + lq[1] + lq[2] + lq[3];
    float mean = S * (1.f / 65536.f);
    float var = Q * (1.f / 65536.f) - mean * mean;
    stats[bg * 2] = mean;
    stats[bg * 2 + 1] = rsqrtf(var + 1e-6f);
  }
}

// ---------------- group norm + transpose: x[b][c][n] -> xnT[b][n][c] bf16 ----
__global__ __launch_bounds__(256) void gn_norm_t(const float* __restrict__ x,
    const float* __restrict__ stats, const float* __restrict__ gamma,
    const float* __restrict__ beta, u16* __restrict__ xnT) {
  __shared__ u16 tile[64][72];
  int b = blockIdx.z;
  int c0 = blockIdx.y * 64, n0 = blockIdx.x * 64;
  int t = threadIdx.x;
  int cl = t >> 2, ng = (t & 3) * 16;
  int c = c0 + cl;
  float mean = stats[(b * 32 + (c >> 4)) * 2];
  float rstd = stats[(b * 32 + (c >> 4)) * 2 + 1];
  float a = gamma[c] * rstd;
  float b2 = beta[c] - mean * a;
  const float* src = x + ((size_t)b * 512 + c) * 4096 + n0 + ng;
  u16 e[16];
  #pragma unroll
  for (int q = 0; q < 4; ++q) {
    float4 v = *(const float4*)(src + q * 4);
    e[q * 4 + 0] = f2bf(v.x * a + b2);
    e[q * 4 + 1] = f2bf(v.y * a + b2);
    e[q * 4 + 2] = f2bf(v.z * a + b2);
    e[q * 4 + 3] = f2bf(v.w * a + b2);
  }
  #pragma unroll
  for (int j = 0; j < 16; ++j) tile[ng + j][cl] = e[j];
  __syncthreads();
  int nl = t >> 2, cg = (t & 3) * 16;
  uint4 w0 = *(const uint4*)&tile[nl][cg];
  uint4 w1 = *(const uint4*)&tile[nl][cg + 8];
  u16* dst = xnT + ((size_t)b * 4096 + n0 + nl) * 512 + c0 + cg;
  *(uint4*)dst = w0;
  *(uint4*)(dst + 8) = w1;
}

// ------------- bf16 NT GEMM: C[m][n] = sum_k A[m*lda+k]*B[n*ldb+k] --------
// 128x128 tile, BK=32, dbuf LDS + global_load_lds.
// EPI: 3 = fp32 out + bias[m] + resid (proj)
//      4 = fp8 out, (acc+bias[n])*scale  (qk: m=spatial, n=channel)
//      5 = fp8 out, acc+bias[m]          (v:  m=channel, n=spatial)
template<int EPI>
__global__ __launch_bounds__(256) void gemm_nt(
    const u16* __restrict__ A, const u16* __restrict__ B,
    int lda, int ldb, int K,
    const float* __restrict__ bias, const float* __restrict__ resid,
    float scale, float* __restrict__ outF, void* __restrict__ outBv, int ldo,
    size_t azs, size_t bzs, size_t ozs) {
  __shared__ __align__(16) u16 smem[16384];
  const size_t z = blockIdx.z;
  A += z * azs; B += z * bzs;
  const int t = threadIdx.x;
  const int wave = t >> 6, lane = t & 63;
  const int wm = wave >> 1, wn = wave & 1;
  const int quad = lane >> 4, li = lane & 15;
  const int m0 = blockIdx.y * 128, n0 = blockIdx.x * 128;

  const int srow = lane >> 2;
  const int scol = (lane & 3) * 8;
  const u16* gA[2];
  const u16* gB[2];
  int ldsOff[2];
  #pragma unroll
  for (int r = 0; r < 2; ++r) {
    int rb = wave + 4 * r;
    gA[r] = A + (size_t)(m0 + rb * 16 + srow) * lda + scol;
    gB[r] = B + (size_t)(n0 + rb * 16 + srow) * ldb + scol;
    ldsOff[r] = rb * 512;
  }

  f32x4 zero = {0.f, 0.f, 0.f, 0.f};
  f32x4 acc[4][4];
  #pragma unroll
  for (int i = 0; i < 4; ++i)
    #pragma unroll
    for (int j = 0; j < 4; ++j) acc[i][j] = zero;

  #pragma unroll
  for (int r = 0; r < 2; ++r) {
    gld_lds16(gA[r], &smem[ldsOff[r]]);
    gld_lds16(gB[r], &smem[8192 + ldsOff[r]]);
  }
  __syncthreads();

  for (int kt = 0; kt < K; kt += 32) {
    const int s = (kt >> 5) & 1;
    if (kt + 32 < K) {
      const int ns = s ^ 1;
      #pragma unroll
      for (int r = 0; r < 2; ++r) {
        gld_lds16(gA[r] + kt + 32, &smem[ns * 4096 + ldsOff[r]]);
        gld_lds16(gB[r] + kt + 32, &smem[8192 + ns * 4096 + ldsOff[r]]);
      }
    }
    bf16x8 af[4], bf[4];
    #pragma unroll
    for (int i = 0; i < 4; ++i) {
      af[i] = *(const bf16x8*)&smem[s * 4096 +
               (wm * 64 + i * 16 + li) * 32 + quad * 8];
      bf[i] = *(const bf16x8*)&smem[8192 + s * 4096 +
               (wn * 64 + i * 16 + li) * 32 + quad * 8];
    }
    #pragma unroll
    for (int i = 0; i < 4; ++i)
      #pragma unroll
      for (int j = 0; j < 4; ++j)
        acc[i][j] = __builtin_amdgcn_mfma_f32_16x16x32_bf16(
            af[i], bf[j], acc[i][j], 0, 0, 0);
    __syncthreads();
  }

  if (EPI == 3) {
    outF += z * ozs; resid += z * ozs;
    #pragma unroll
    for (int i = 0; i < 4; ++i)
      #pragma unroll
      for (int j = 0; j < 4; ++j) {
        int mB = m0 + wm * 64 + i * 16 + quad * 4;
        int n = n0 + wn * 64 + j * 16 + li;
        #pragma unroll
        for (int r = 0; r < 4; ++r) {
          int m = mB + r;
          float v = acc[i][j][r] + bias[m] + resid[(size_t)m * ldo + n];
          outF[(size_t)m * ldo + n] = v;
        }
      }
    return;
  }

  // fp8 outputs (EPI 4/5): bounce through LDS, coalesced stores
  u8* out8 = (u8*)outBv + z * ozs;
  u8* bnc = (u8*)smem;
  #pragma unroll
  for (int i = 0; i < 4; ++i) {
    int lm = wm * 64 + i * 16 + quad * 4;
    #pragma unroll
    for (int j = 0; j < 4; ++j) {
      int ln = wn * 64 + j * 16 + li;
      #pragma unroll
      for (int r = 0; r < 4; ++r) {
        float v = acc[i][j][r];
        u8 o;
        if (EPI == 4) o = f2f8((v + bias[n0 + ln]) * scale);
        else          o = f2f8(v + bias[m0 + lm + r]);
        bnc[(lm + r) * 144 + ln] = o;
      }
    }
  }
  __syncthreads();
  {
    int row = t >> 1, half = t & 1;
    const u8* src = &bnc[row * 144 + half * 64];
    u8* dst = out8 + (size_t)(m0 + row) * ldo + n0 + half * 64;
    #pragma unroll
    for (int cc = 0; cc < 4; ++cc)
      *(uint4*)(dst + cc * 16) = *(const uint4*)(src + cc * 16);
  }
}

// ------------- PV fp8 NT GEMM (EPI6): 128x128, BK=64, 3-stage -------------
// (R7-proven: BK=64 halved PV's step count, ~120 -> ~82 us.)
template<int EPI, int SWZ>
__global__ __launch_bounds__(256) void gemm_nt8(
    const u8* __restrict__ A, const u8* __restrict__ B,
    int lda, int ldb, int K,
    const float* __restrict__ rsum, float* __restrict__ outF,
    void* __restrict__ outBv, int ldo,
    size_t azs, size_t bzs, size_t ozs) {
  __shared__ __align__(16) u8 smem[49152];
  const size_t z = blockIdx.z;
  A += z * azs; B += z * bzs;
  int bx = blockIdx.x, by = blockIdx.y;
  if (SWZ) {
    int lin = by * 32 + bx;
    int tt = lin >> 8, w = lin & 255;
    by = (tt >> 1) * 16 + (w >> 4);
    bx = (tt & 1) * 16 + (w & 15);
  }
  const int t = threadIdx.x;
  const int wave = t >> 6, lane = t & 63;
  const int wm = wave >> 1, wn = wave & 1;
  const int quad = lane >> 4, li = lane & 15;
  const int m0 = by * 128, n0 = bx * 128;

  const int us = lane ^ ((lane >> 3) & 7);
  const int srow = (us >> 1) & 31;
  const int shalf = us & 1;
  const u8* gA = A + (size_t)(m0 + wave * 32 + srow) * lda + shalf * 16;
  const u8* gB = B + (size_t)(n0 + wave * 32 + srow) * ldb + shalf * 16;
  const int ldsOff = wave * 1024;

  const int h = quad >> 1, qlo = (quad & 1) * 8;
  int aoff[4], boff[4];
  #pragma unroll
  for (int i = 0; i < 4; ++i) {
    int r5 = (i & 1) * 16 + li;
    int p = (2 * r5 + h) ^ ((r5 >> 2) & 7);
    aoff[i] = (wm * 2 + (i >> 1)) * 1024 + p * 16 + qlo;
    boff[i] = (wn * 2 + (i >> 1)) * 1024 + p * 16 + qlo;
  }

  f32x4 zero = {0.f, 0.f, 0.f, 0.f};
  f32x4 acc[4][4];
  #pragma unroll
  for (int i = 0; i < 4; ++i)
    #pragma unroll
    for (int j = 0; j < 4; ++j) acc[i][j] = zero;

  #pragma unroll
  for (int p = 0; p < 2; ++p) {
    gld_lds16(gA + p * 64,      &smem[p * 8192 + ldsOff]);
    gld_lds16(gA + p * 64 + 32, &smem[p * 8192 + 4096 + ldsOff]);
    gld_lds16(gB + p * 64,      &smem[24576 + p * 8192 + ldsOff]);
    gld_lds16(gB + p * 64 + 32, &smem[24576 + p * 8192 + 4096 + ldsOff]);
  }
  __builtin_amdgcn_sched_barrier(0);
  asm volatile("s_waitcnt vmcnt(4)");
  bar();

  int s = 0;
  for (int kt = 0; kt < K; kt += 64) {
    if (kt + 128 < K) {
      const int ns = (s == 0) ? 2 : s - 1;  // (s+2)%3
      gld_lds16(gA + kt + 128,      &smem[ns * 8192 + ldsOff]);
      gld_lds16(gA + kt + 128 + 32, &smem[ns * 8192 + 4096 + ldsOff]);
      gld_lds16(gB + kt + 128,      &smem[24576 + ns * 8192 + ldsOff]);
      gld_lds16(gB + kt + 128 + 32, &smem[24576 + ns * 8192 + 4096 + ldsOff]);
    }
    const int sb = s * 8192;
    long af[4][2], bf[4][2];
    #pragma unroll
    for (int i = 0; i < 4; ++i) {
      #pragma unroll
      for (int g = 0; g < 2; ++g) {
        af[i][g] = *(const long*)&smem[sb + g * 4096 + aoff[i]];
        bf[i][g] = *(const long*)&smem[24576 + sb + g * 4096 + boff[i]];
      }
    }
    #pragma unroll
    for (int i = 0; i < 4; ++i)
      #pragma unroll
      for (int j = 0; j < 4; ++j) {
        acc[i][j] = __builtin_amdgcn_mfma_f32_16x16x32_fp8_fp8(
            af[i][0], bf[j][0], acc[i][j], 0, 0, 0);
        acc[i][j] = __builtin_amdgcn_mfma_f32_16x16x32_fp8_fp8(
            af[i][1], bf[j][1], acc[i][j], 0, 0, 0);
      }
    if (kt + 64 < K) {
      __builtin_amdgcn_sched_barrier(0);
      if (kt + 128 < K) asm volatile("s_waitcnt vmcnt(4)");
      else              asm volatile("s_waitcnt vmcnt(0)");
      bar();
    }
    s = (s == 2) ? 0 : s + 1;
  }
  __syncthreads();

  {  // EPI 6: PV epilogue
    const float* rsF = rsum + z * 4096;
    u16* outp = (u16*)outBv + z * ozs;
    u16* b16 = (u16*)smem;
    #pragma unroll
    for (int i = 0; i < 4; ++i) {
      int lm = wm * 64 + i * 16 + quad * 4;
      float rinv[4];
      #pragma unroll
      for (int r = 0; r < 4; ++r)
        rinv[r] = __builtin_amdgcn_rcpf(rsF[m0 + lm + r]);
      #pragma unroll
      for (int j = 0; j < 4; ++j) {
        int ln = wn * 64 + j * 16 + li;
        #pragma unroll
        for (int r = 0; r < 4; ++r)
          b16[(lm + r) * 136 + ln] = f2bf(acc[i][j][r] * rinv[r]);
      }
    }
    __syncthreads();
    int row = t >> 1, half = t & 1;
    const u16* src = &b16[row * 136 + half * 64];
    u16* dst = outp + (size_t)(m0 + row) * ldo + n0 + half * 64;
    #pragma unroll
    for (int cc = 0; cc < 8; ++cc)
      *(uint4*)(dst + cc * 8) = *(const uint4*)(src + cc * 8);
  }
}

// ------------- QK^T 256x128-tile fp8 GEMM + exp + rowsum ------------------
// Discriminating experiment after 7 rounds of flat ~120 us: QK's per-step
// cost (~2250 cyc at BK=64) is invariant to conflicts/waits/occupancy/step
// count.  This kernel doubles MFMA per step at FIXED step count (8):
// 256x128 tile, 4 waves each owning 64 rows x all 128 cols (acc 4x8,
// 128 AGPR), BK=64, 3-stage counted pipeline (72KB LDS -> 2 blocks/CU).
// Same swizzle scheme; same panel0->panel1 k-ascending accumulation order
// per output element (bit-identical E vs R7).  Blocks halve to 2048; B-side
// logical traffic halves.
__global__ __launch_bounds__(256) void qk256(
    const u8* __restrict__ A, const u8* __restrict__ B,
    float* __restrict__ rowsum, u8* __restrict__ outE) {
  // LDS: A stages s*16384 in [0,49152): panel g at g*8192, region r(0..7)*1024
  //      B stages 49152+s*8192 in [49152,73728): panel g at g*4096, region
  //      r(0..3)*1024.  Epilogue bounce u8[256][144]=36864 overlays [0,..).
  __shared__ __align__(16) u8 smem[73728];
  const int lda = 1024, K = 512;
  const size_t z = blockIdx.z;
  A += (size_t)z * 4096 * 1024;
  B += (size_t)z * 4096 * 1024;
  float* rsF = rowsum + (size_t)z * 4096;
  u8* outp = outE + (size_t)z * 4096 * 4096;

  const int t = threadIdx.x;
  const int w = t >> 6, lane = t & 63;
  const int quad = lane >> 4, li = lane & 15;
  const int m0 = blockIdx.y * 256, n0 = blockIdx.x * 128;

  // staging (pre-swizzled global source, linear LDS dest)
  const int us = lane ^ ((lane >> 3) & 7);
  const int srow = (us >> 1) & 31;
  const int shalf = us & 1;
  const u8* gA0 = A + (size_t)(m0 + w * 64 + srow) * lda + shalf * 16;
  const u8* gA1 = gA0 + (size_t)32 * lda;
  const u8* gB  = B + (size_t)(n0 + w * 32 + srow) * lda + shalf * 16;

  // frag read offsets: p = (2*r5+h) ^ ((r5>>2)&7) within a 1KB region
  const int h = quad >> 1, qlo = (quad & 1) * 8;
  int aoff[4], boff[8];
  #pragma unroll
  for (int i = 0; i < 4; ++i) {
    int r5 = (i & 1) * 16 + li;
    int p = (2 * r5 + h) ^ ((r5 >> 2) & 7);
    aoff[i] = (2 * w + (i >> 1)) * 1024 + p * 16 + qlo;
  }
  #pragma unroll
  for (int j = 0; j < 8; ++j) {
    int r5 = (j & 1) * 16 + li;
    int p = (2 * r5 + h) ^ ((r5 >> 2) & 7);
    boff[j] = (j >> 1) * 1024 + p * 16 + qlo;
  }

  f32x4 zero = {0.f, 0.f, 0.f, 0.f};
  f32x4 acc[4][8];
  #pragma unroll
  for (int i = 0; i < 4; ++i)
    #pragma unroll
    for (int j = 0; j < 8; ++j) acc[i][j] = zero;

  // stage one BK=64 step (6 gld/wave: A r0/r1 x panel g, B x panel g)
  auto STAGE = [&](int kt, int st) {
    int sA = st * 16384, sB = 49152 + st * 8192;
    #pragma unroll
    for (int g = 0; g < 2; ++g) {
      gld_lds16(gA0 + kt + g * 32, &smem[sA + g * 8192 + (2 * w) * 1024]);
      gld_lds16(gA1 + kt + g * 32, &smem[sA + g * 8192 + (2 * w + 1) * 1024]);
      gld_lds16(gB  + kt + g * 32, &smem[sB + g * 4096 + w * 1024]);
    }
  };

  STAGE(0, 0);
  STAGE(64, 1);
  __builtin_amdgcn_sched_barrier(0);
  asm volatile("s_waitcnt vmcnt(6)");
  bar();

  int s = 0;
  for (int kt = 0; kt < K; kt += 64) {
    if (kt + 128 < K) STAGE(kt + 128, (s == 0) ? 2 : s - 1);
    const int sA = s * 16384, sB = 49152 + s * 8192;
    long af[4][2];
    #pragma unroll
    for (int i = 0; i < 4; ++i)
      #pragma unroll
      for (int g = 0; g < 2; ++g)
        af[i][g] = *(const long*)&smem[sA + g * 8192 + aoff[i]];
    #pragma unroll
    for (int j = 0; j < 8; ++j) {
      long b0 = *(const long*)&smem[sB + boff[j]];
      long b1 = *(const long*)&smem[sB + 4096 + boff[j]];
      #pragma unroll
      for (int i = 0; i < 4; ++i) {
        acc[i][j] = __builtin_amdgcn_mfma_f32_16x16x32_fp8_fp8(
            af[i][0], b0, acc[i][j], 0, 0, 0);
        acc[i][j] = __builtin_amdgcn_mfma_f32_16x16x32_fp8_fp8(
            af[i][1], b1, acc[i][j], 0, 0, 0);
      }
    }
    if (kt + 64 < K) {
      __builtin_amdgcn_sched_barrier(0);
      if (kt + 128 < K) asm volatile("s_waitcnt vmcnt(6)");
      else              asm volatile("s_waitcnt vmcnt(0)");
      bar();
    }
    s = (s == 2) ? 0 : s + 1;
  }
  __syncthreads();  // all waves done reading stages before bounce overlay

  // epilogue: exp + clamp, rowsum atomics, fp8 bounce + stores
  #pragma unroll
  for (int i = 0; i < 4; ++i) {
    int lm = w * 64 + i * 16 + quad * 4;
    float rs[4] = {0.f, 0.f, 0.f, 0.f};
    #pragma unroll
    for (int j = 0; j < 8; ++j) {
      int ln = j * 16 + li;
      #pragma unroll
      for (int r = 0; r < 4; ++r) {
        float e = fminf(__expf(acc[i][j][r]), 448.f);
        smem[(lm + r) * 144 + ln] = f2f8(e);
        rs[r] += e;
      }
    }
    #pragma unroll
    for (int r = 0; r < 4; ++r) {
      rs[r] += __shfl_xor(rs[r], 1);
      rs[r] += __shfl_xor(rs[r], 2);
      rs[r] += __shfl_xor(rs[r], 4);
      rs[r] += __shfl_xor(rs[r], 8);
    }
    if (li == 0) {
      #pragma unroll
      for (int r = 0; r < 4; ++r) atomicAdd(&rsF[m0 + lm + r], rs[r]);
    }
  }
  __syncthreads();
  {
    int row = t;  // 256 threads, 256 rows
    const u8* src = &smem[row * 144];
    u8* dst = outp + (size_t)(m0 + row) * 4096 + n0;
    #pragma unroll
    for (int cc = 0; cc < 8; ++cc)
      *(uint4*)(dst + cc * 16) = *(const uint4*)(src + cc * 16);
  }
}

extern "C" void kernel_launch(void* const* d_in, const int* in_sizes, int n_in,
                              void* d_out, int out_size, void* d_ws, size_t ws_size,
                              hipStream_t stream) {
  (void)in_sizes; (void)n_in; (void)out_size; (void)ws_size;
  const float* x      = (const float*)d_in[0];
  const float* gamma  = (const float*)d_in[1];
  const float* beta   = (const float*)d_in[2];
  const float* w_qkv  = (const float*)d_in[3];
  const float* b_qkv  = (const float*)d_in[4];
  const float* w_proj = (const float*)d_in[5];
  const float* b_proj = (const float*)d_in[6];
  float* out = (float*)d_out;

  const int C = 512, N = 4096;
  const size_t NC = (size_t)N * C;
  const float scale = 0.21022410381342863f;  // 512^-0.25

  char* ws = (char*)d_ws;
  size_t off = 0;
  auto alloc = [&](size_t bytes) -> char* {
    char* p = ws + off; off += (bytes + 255) & ~(size_t)255; return p;
  };
  u16*   wq_bf  = (u16*)alloc((size_t)1536 * 512 * 2);
  u16*   wp_bf  = (u16*)alloc((size_t)512 * 512 * 2);
  float* stats  = (float*)alloc(128 * 2 * 4);
  float* rowsum = (float*)alloc((size_t)4 * N * 4);
  u16*   xnT    = (u16*)alloc((size_t)4 * NC * 2);      // [b][n][c] bf16
  u8*    qkT    = (u8*)alloc((size_t)4 * N * 1024);     // [b][i][o] fp8, o<1024
  u8*    vbf    = (u8*)alloc((size_t)4 * 512 * 4096);   // [b][c][j] fp8
  u16*   ao     = (u16*)alloc((size_t)4 * NC * 2);      // [b][i][c] bf16
  u8*    E      = (u8*)alloc((size_t)4 * N * N);        // [b][i][j] fp8

  cvt_weights<<<3072, 256, 0, stream>>>(w_qkv, w_proj, wq_bf, wp_bf);
  gn_stats<<<128, 256, 0, stream>>>(x, stats);
  gn_norm_t<<<dim3(64, 8, 4), 256, 0, stream>>>(x, stats, gamma, beta, xnT);
  hipMemsetAsync(rowsum, 0, (size_t)4 * N * 4, stream);

  // qkT[b][i][o] = fp8((sum_c xnT[b][i][c]*wq[o][c] + b_qkv[o]) * scale)
  gemm_nt<4><<<dim3(8, 32, 4), 256, 0, stream>>>(
      xnT, wq_bf, 512, 512, 512, b_qkv, nullptr, scale,
      nullptr, qkT, 1024, NC, 0, (size_t)N * 1024);
  // vbf[b][c][j] = fp8(sum_k wq[1024+c][k]*xnT[b][j][k] + b_qkv[1024+c])
  gemm_nt<5><<<dim3(32, 4, 4), 256, 0, stream>>>(
      wq_bf + (size_t)1024 * 512, xnT, 512, 512, 512, b_qkv + 1024, nullptr,
      0.f, nullptr, vbf, 4096, 0, NC, (size_t)512 * 4096);
  // E[b][i][j] = fp8(exp(S)), rowsum[b][i] += partials (256x128 tiles)
  qk256<<<dim3(32, 16, 4), 256, 0, stream>>>(qkT, qkT + 512, rowsum, E);
  // ao[b][i][c] = bf16((sum_j E*v) * rcp(rowsum[b][i]))  (BK=64, 64 steps)
  gemm_nt8<6, 0><<<dim3(4, 32, 4), 256, 0, stream>>>(
      E, vbf, 4096, 4096, 4096, rowsum, nullptr,
      ao, 512, (size_t)N * N, (size_t)512 * 4096, NC);
  // out[b][o][n] = sum_c wp[o][c]*ao[b][n][c] + b_proj[o] + x[b][o][n]
  gemm_nt<3><<<dim3(32, 4, 4), 256, 0, stream>>>(
      wp_bf, ao, 512, 512, 512, b_proj, x, 0.f,
      out, nullptr, 4096, 0, NC, NC);
}

// Round 9
// 378.838 us; speedup vs baseline: 1.0377x; 1.0377x over previous
//
#include <hip/hip_runtime.h>
#include <hip/hip_fp8.h>
#include <stdint.h>

typedef unsigned short u16;
typedef unsigned char u8;
typedef __bf16 bf16x8 __attribute__((ext_vector_type(8)));
typedef float f32x4 __attribute__((ext_vector_type(4)));

__device__ __forceinline__ u16 f2bf(float f) {
  union { float f; unsigned u; } v; v.f = f;
  return (u16)((v.u + 0x7FFFu + ((v.u >> 16) & 1u)) >> 16);
}
__device__ __forceinline__ u8 f2f8(float f) {
  __hip_fp8_e4m3 h(f);
  return (u8)h.__x;
}

// async 16B global -> LDS (wave-uniform LDS base; HW writes base + lane*16)
__device__ __forceinline__ void gld_lds16(const void* g, void* l) {
  uint32_t lo = (uint32_t)(uintptr_t)l;
  lo = __builtin_amdgcn_readfirstlane(lo);
  auto* lp = (__attribute__((address_space(3))) uint32_t*)(uintptr_t)lo;
  auto* gp = (const __attribute__((address_space(1))) uint32_t*)(uintptr_t)g;
  __builtin_amdgcn_global_load_lds(gp, lp, 16, 0, 0);
}

// clobber-free barrier, fenced so no memory op crosses at schedule time.
__device__ __forceinline__ void bar() {
  __builtin_amdgcn_sched_barrier(0);
  __builtin_amdgcn_s_barrier();
  __builtin_amdgcn_sched_barrier(0);
}

// ---------------- weight fp32 -> bf16 ----------------
__global__ __launch_bounds__(256) void cvt_weights(
    const float* __restrict__ wq, const float* __restrict__ wp,
    u16* __restrict__ oq, u16* __restrict__ op) {
  int i = blockIdx.x * 256 + threadIdx.x;
  if (i < 1536 * 512) oq[i] = f2bf(wq[i]);
  if (i < 512 * 512)  op[i] = f2bf(wp[i]);
}

// ---------------- group norm stats ----------------
__global__ __launch_bounds__(256) void gn_stats(const float* __restrict__ x,
                                                float* __restrict__ stats) {
  int bg = blockIdx.x;  // 0..127
  const float* p = x + (size_t)bg * 65536;
  float s = 0.f, sq = 0.f;
  for (int i = threadIdx.x * 4; i < 65536; i += 1024) {
    float4 v = *(const float4*)(p + i);
    s += v.x + v.y + v.z + v.w;
    sq += v.x * v.x + v.y * v.y + v.z * v.z + v.w * v.w;
  }
  int lane = threadIdx.x & 63, w = threadIdx.x >> 6;
  for (int off = 32; off; off >>= 1) {
    s += __shfl_down(s, off);
    sq += __shfl_down(sq, off);
  }
  __shared__ float ls[4], lq[4];
  if (lane == 0) { ls[w] = s; lq[w] = sq; }
  __syncthreads();
  if (threadIdx.x == 0) {
    float S = ls[0] + ls[1] + ls[2] + ls[3];
    float Q = lq[0] + lq[1] + lq[2] + lq[3];
    float mean = S * (1.f / 65536.f);
    float var = Q * (1.f / 65536.f) - mean * mean;
    stats[bg * 2] = mean;
    stats[bg * 2 + 1] = rsqrtf(var + 1e-6f);
  }
}

// ---------------- group norm + transpose: x[b][c][n] -> xnT[b][n][c] bf16 ----
__global__ __launch_bounds__(256) void gn_norm_t(const float* __restrict__ x,
    const float* __restrict__ stats, const float* __restrict__ gamma,
    const float* __restrict__ beta, u16* __restrict__ xnT) {
  __shared__ u16 tile[64][72];
  int b = blockIdx.z;
  int c0 = blockIdx.y * 64, n0 = blockIdx.x * 64;
  int t = threadIdx.x;
  int cl = t >> 2, ng = (t & 3) * 16;
  int c = c0 + cl;
  float mean = stats[(b * 32 + (c >> 4)) * 2];
  float rstd = stats[(b * 32 + (c >> 4)) * 2 + 1];
  float a = gamma[c] * rstd;
  float b2 = beta[c] - mean * a;
  const float* src = x + ((size_t)b * 512 + c) * 4096 + n0 + ng;
  u16 e[16];
  #pragma unroll
  for (int q = 0; q < 4; ++q) {
    float4 v = *(const float4*)(src + q * 4);
    e[q * 4 + 0] = f2bf(v.x * a + b2);
    e[q * 4 + 1] = f2bf(v.y * a + b2);
    e[q * 4 + 2] = f2bf(v.z * a + b2);
    e[q * 4 + 3] = f2bf(v.w * a + b2);
  }
  #pragma unroll
  for (int j = 0; j < 16; ++j) tile[ng + j][cl] = e[j];
  __syncthreads();
  int nl = t >> 2, cg = (t & 3) * 16;
  uint4 w0 = *(const uint4*)&tile[nl][cg];
  uint4 w1 = *(const uint4*)&tile[nl][cg + 8];
  u16* dst = xnT + ((size_t)b * 4096 + n0 + nl) * 512 + c0 + cg;
  *(uint4*)dst = w0;
  *(uint4*)(dst + 8) = w1;
}

// ------------- bf16 NT GEMM: C[m][n] = sum_k A[m*lda+k]*B[n*ldb+k] --------
// 128x128 tile, BK=32, dbuf LDS + global_load_lds.
// EPI: 3 = fp32 out + bias[m] + resid (proj)
//      4 = fp8 out, (acc+bias[n])*scale  (qk: m=spatial, n=channel)
//      5 = fp8 out, acc+bias[m]          (v:  m=channel, n=spatial)
template<int EPI>
__global__ __launch_bounds__(256) void gemm_nt(
    const u16* __restrict__ A, const u16* __restrict__ B,
    int lda, int ldb, int K,
    const float* __restrict__ bias, const float* __restrict__ resid,
    float scale, float* __restrict__ outF, void* __restrict__ outBv, int ldo,
    size_t azs, size_t bzs, size_t ozs) {
  __shared__ __align__(16) u16 smem[16384];
  const size_t z = blockIdx.z;
  A += z * azs; B += z * bzs;
  const int t = threadIdx.x;
  const int wave = t >> 6, lane = t & 63;
  const int wm = wave >> 1, wn = wave & 1;
  const int quad = lane >> 4, li = lane & 15;
  const int m0 = blockIdx.y * 128, n0 = blockIdx.x * 128;

  const int srow = lane >> 2;
  const int scol = (lane & 3) * 8;
  const u16* gA[2];
  const u16* gB[2];
  int ldsOff[2];
  #pragma unroll
  for (int r = 0; r < 2; ++r) {
    int rb = wave + 4 * r;
    gA[r] = A + (size_t)(m0 + rb * 16 + srow) * lda + scol;
    gB[r] = B + (size_t)(n0 + rb * 16 + srow) * ldb + scol;
    ldsOff[r] = rb * 512;
  }

  f32x4 zero = {0.f, 0.f, 0.f, 0.f};
  f32x4 acc[4][4];
  #pragma unroll
  for (int i = 0; i < 4; ++i)
    #pragma unroll
    for (int j = 0; j < 4; ++j) acc[i][j] = zero;

  #pragma unroll
  for (int r = 0; r < 2; ++r) {
    gld_lds16(gA[r], &smem[ldsOff[r]]);
    gld_lds16(gB[r], &smem[8192 + ldsOff[r]]);
  }
  __syncthreads();

  for (int kt = 0; kt < K; kt += 32) {
    const int s = (kt >> 5) & 1;
    if (kt + 32 < K) {
      const int ns = s ^ 1;
      #pragma unroll
      for (int r = 0; r < 2; ++r) {
        gld_lds16(gA[r] + kt + 32, &smem[ns * 4096 + ldsOff[r]]);
        gld_lds16(gB[r] + kt + 32, &smem[8192 + ns * 4096 + ldsOff[r]]);
      }
    }
    bf16x8 af[4], bf[4];
    #pragma unroll
    for (int i = 0; i < 4; ++i) {
      af[i] = *(const bf16x8*)&smem[s * 4096 +
               (wm * 64 + i * 16 + li) * 32 + quad * 8];
      bf[i] = *(const bf16x8*)&smem[8192 + s * 4096 +
               (wn * 64 + i * 16 + li) * 32 + quad * 8];
    }
    #pragma unroll
    for (int i = 0; i < 4; ++i)
      #pragma unroll
      for (int j = 0; j < 4; ++j)
        acc[i][j] = __builtin_amdgcn_mfma_f32_16x16x32_bf16(
            af[i], bf[j], acc[i][j], 0, 0, 0);
    __syncthreads();
  }

  if (EPI == 3) {
    outF += z * ozs; resid += z * ozs;
    #pragma unroll
    for (int i = 0; i < 4; ++i)
      #pragma unroll
      for (int j = 0; j < 4; ++j) {
        int mB = m0 + wm * 64 + i * 16 + quad * 4;
        int n = n0 + wn * 64 + j * 16 + li;
        #pragma unroll
        for (int r = 0; r < 4; ++r) {
          int m = mB + r;
          float v = acc[i][j][r] + bias[m] + resid[(size_t)m * ldo + n];
          outF[(size_t)m * ldo + n] = v;
        }
      }
    return;
  }

  // fp8 outputs (EPI 4/5): bounce through LDS, coalesced stores
  u8* out8 = (u8*)outBv + z * ozs;
  u8* bnc = (u8*)smem;
  #pragma unroll
  for (int i = 0; i < 4; ++i) {
    int lm = wm * 64 + i * 16 + quad * 4;
    #pragma unroll
    for (int j = 0; j < 4; ++j) {
      int ln = wn * 64 + j * 16 + li;
      #pragma unroll
      for (int r = 0; r < 4; ++r) {
        float v = acc[i][j][r];
        u8 o;
        if (EPI == 4) o = f2f8((v + bias[n0 + ln]) * scale);
        else          o = f2f8(v + bias[m0 + lm + r]);
        bnc[(lm + r) * 144 + ln] = o;
      }
    }
  }
  __syncthreads();
  {
    int row = t >> 1, half = t & 1;
    const u8* src = &bnc[row * 144 + half * 64];
    u8* dst = out8 + (size_t)(m0 + row) * ldo + n0 + half * 64;
    #pragma unroll
    for (int cc = 0; cc < 4; ++cc)
      *(uint4*)(dst + cc * 16) = *(const uint4*)(src + cc * 16);
  }
}

// ------------- PV fp8 NT GEMM (EPI6): 128x128, BK=64, 3-stage -------------
// (R7-proven: BK=64 halved PV's step count, ~120 -> ~82 us.)
template<int EPI, int SWZ>
__global__ __launch_bounds__(256) void gemm_nt8(
    const u8* __restrict__ A, const u8* __restrict__ B,
    int lda, int ldb, int K,
    const float* __restrict__ rsum, float* __restrict__ outF,
    void* __restrict__ outBv, int ldo,
    size_t azs, size_t bzs, size_t ozs) {
  __shared__ __align__(16) u8 smem[49152];
  const size_t z = blockIdx.z;
  A += z * azs; B += z * bzs;
  int bx = blockIdx.x, by = blockIdx.y;
  if (SWZ) {
    int lin = by * 32 + bx;
    int tt = lin >> 8, w = lin & 255;
    by = (tt >> 1) * 16 + (w >> 4);
    bx = (tt & 1) * 16 + (w & 15);
  }
  const int t = threadIdx.x;
  const int wave = t >> 6, lane = t & 63;
  const int wm = wave >> 1, wn = wave & 1;
  const int quad = lane >> 4, li = lane & 15;
  const int m0 = by * 128, n0 = bx * 128;

  const int us = lane ^ ((lane >> 3) & 7);
  const int srow = (us >> 1) & 31;
  const int shalf = us & 1;
  const u8* gA = A + (size_t)(m0 + wave * 32 + srow) * lda + shalf * 16;
  const u8* gB = B + (size_t)(n0 + wave * 32 + srow) * ldb + shalf * 16;
  const int ldsOff = wave * 1024;

  const int h = quad >> 1, qlo = (quad & 1) * 8;
  int aoff[4], boff[4];
  #pragma unroll
  for (int i = 0; i < 4; ++i) {
    int r5 = (i & 1) * 16 + li;
    int p = (2 * r5 + h) ^ ((r5 >> 2) & 7);
    aoff[i] = (wm * 2 + (i >> 1)) * 1024 + p * 16 + qlo;
    boff[i] = (wn * 2 + (i >> 1)) * 1024 + p * 16 + qlo;
  }

  f32x4 zero = {0.f, 0.f, 0.f, 0.f};
  f32x4 acc[4][4];
  #pragma unroll
  for (int i = 0; i < 4; ++i)
    #pragma unroll
    for (int j = 0; j < 4; ++j) acc[i][j] = zero;

  #pragma unroll
  for (int p = 0; p < 2; ++p) {
    gld_lds16(gA + p * 64,      &smem[p * 8192 + ldsOff]);
    gld_lds16(gA + p * 64 + 32, &smem[p * 8192 + 4096 + ldsOff]);
    gld_lds16(gB + p * 64,      &smem[24576 + p * 8192 + ldsOff]);
    gld_lds16(gB + p * 64 + 32, &smem[24576 + p * 8192 + 4096 + ldsOff]);
  }
  __builtin_amdgcn_sched_barrier(0);
  asm volatile("s_waitcnt vmcnt(4)");
  bar();

  int s = 0;
  for (int kt = 0; kt < K; kt += 64) {
    if (kt + 128 < K) {
      const int ns = (s == 0) ? 2 : s - 1;  // (s+2)%3
      gld_lds16(gA + kt + 128,      &smem[ns * 8192 + ldsOff]);
      gld_lds16(gA + kt + 128 + 32, &smem[ns * 8192 + 4096 + ldsOff]);
      gld_lds16(gB + kt + 128,      &smem[24576 + ns * 8192 + ldsOff]);
      gld_lds16(gB + kt + 128 + 32, &smem[24576 + ns * 8192 + 4096 + ldsOff]);
    }
    const int sb = s * 8192;
    long af[4][2], bf[4][2];
    #pragma unroll
    for (int i = 0; i < 4; ++i) {
      #pragma unroll
      for (int g = 0; g < 2; ++g) {
        af[i][g] = *(const long*)&smem[sb + g * 4096 + aoff[i]];
        bf[i][g] = *(const long*)&smem[24576 + sb + g * 4096 + boff[i]];
      }
    }
    #pragma unroll
    for (int i = 0; i < 4; ++i)
      #pragma unroll
      for (int j = 0; j < 4; ++j) {
        acc[i][j] = __builtin_amdgcn_mfma_f32_16x16x32_fp8_fp8(
            af[i][0], bf[j][0], acc[i][j], 0, 0, 0);
        acc[i][j] = __builtin_amdgcn_mfma_f32_16x16x32_fp8_fp8(
            af[i][1], bf[j][1], acc[i][j], 0, 0, 0);
      }
    if (kt + 64 < K) {
      __builtin_amdgcn_sched_barrier(0);
      if (kt + 128 < K) asm volatile("s_waitcnt vmcnt(4)");
      else              asm volatile("s_waitcnt vmcnt(0)");
      bar();
    }
    s = (s == 2) ? 0 : s + 1;
  }
  __syncthreads();

  {  // EPI 6: PV epilogue
    const float* rsF = rsum + z * 4096;
    u16* outp = (u16*)outBv + z * ozs;
    u16* b16 = (u16*)smem;
    #pragma unroll
    for (int i = 0; i < 4; ++i) {
      int lm = wm * 64 + i * 16 + quad * 4;
      float rinv[4];
      #pragma unroll
      for (int r = 0; r < 4; ++r)
        rinv[r] = __builtin_amdgcn_rcpf(rsF[m0 + lm + r]);
      #pragma unroll
      for (int j = 0; j < 4; ++j) {
        int ln = wn * 64 + j * 16 + li;
        #pragma unroll
        for (int r = 0; r < 4; ++r)
          b16[(lm + r) * 136 + ln] = f2bf(acc[i][j][r] * rinv[r]);
      }
    }
    __syncthreads();
    int row = t >> 1, half = t & 1;
    const u16* src = &b16[row * 136 + half * 64];
    u16* dst = outp + (size_t)(m0 + row) * ldo + n0 + half * 64;
    #pragma unroll
    for (int cc = 0; cc < 8; ++cc)
      *(uint4*)(dst + cc * 8) = *(const uint4*)(src + cc * 8);
  }
}

// ------------- QK^T strip kernel: long-lived blocks --------------------
// Evidence from R0-R8: every short-K (8-16 step) block runs ~570 TF while
// PV's 64-step blocks run ~840 TF — the binding cost is per-BLOCK
// (prologue cold-miss, epilogue serialization, multi-round packing), not
// per-step.  Fix: each block owns a 128-row i-tile x 1024-col n-strip
// (8 n-tiles) and runs ONE flat 64-step pipelined loop (8 nt x 8 K-steps,
// BK=64).  Grid 512 blocks = exactly 2/CU, single round.  At nt
// boundaries the epilogue (exp -> fp8 bounce -> coalesced store) runs in
// a dedicated LDS region with clobber-free lgkmcnt(0)+s_barrier (no
// __syncthreads -> no vmcnt drain) while the next nt's stages stay in
// flight; boundary wait = vmcnt(8) to discount the epilogue's own stores.
// Rowsum atomics deferred past the loop (counted vmcnt stays clean).
// Per-(i,j) accumulation order identical to R7 -> same E bits.
__global__ __launch_bounds__(256) void qk_strip(
    const u8* __restrict__ A, const u8* __restrict__ B,
    float* __restrict__ rowsum, u8* __restrict__ outE) {
  // LDS: A stages s*8192 [0,24576), B 24576+s*8192 [24576,49152),
  //      epilogue bounce u8[128][144] at [49152,67584).
  __shared__ __align__(16) u8 smem[67584];
  const int lda = 1024;
  const size_t z = blockIdx.z;
  A += (size_t)z * 4096 * 1024;
  B += (size_t)z * 4096 * 1024;
  float* rsF = rowsum + (size_t)z * 4096;
  u8* outp = outE + (size_t)z * 4096 * 4096;

  const int t = threadIdx.x;
  const int wave = t >> 6, lane = t & 63;
  const int wm = wave >> 1, wn = wave & 1;
  const int quad = lane >> 4, li = lane & 15;
  const int m0 = blockIdx.y * 128;
  const int nbase = blockIdx.x * 1024;  // 8 n-tiles of 128

  // staging (pre-swizzled global source, linear LDS dest)
  const int us = lane ^ ((lane >> 3) & 7);
  const int srow = (us >> 1) & 31;
  const int shalf = us & 1;
  const u8* gA = A + (size_t)(m0 + wave * 32 + srow) * lda + shalf * 16;
  const u8* gBb = B + (size_t)(nbase + wave * 32 + srow) * lda + shalf * 16;
  const int ldsOff = wave * 1024;

  // frag read offsets (identical to gemm_nt8 BK=64)
  const int h = quad >> 1, qlo = (quad & 1) * 8;
  int aoff[4], boff[4];
  #pragma unroll
  for (int i = 0; i < 4; ++i) {
    int r5 = (i & 1) * 16 + li;
    int p = (2 * r5 + h) ^ ((r5 >> 2) & 7);
    aoff[i] = (wm * 2 + (i >> 1)) * 1024 + p * 16 + qlo;
    boff[i] = (wn * 2 + (i >> 1)) * 1024 + p * 16 + qlo;
  }

  f32x4 zero = {0.f, 0.f, 0.f, 0.f};
  f32x4 acc[4][4];
  #pragma unroll
  for (int i = 0; i < 4; ++i)
    #pragma unroll
    for (int j = 0; j < 4; ++j) acc[i][j] = zero;
  float rs_tot[4][4];
  #pragma unroll
  for (int i = 0; i < 4; ++i)
    #pragma unroll
    for (int r = 0; r < 4; ++r) rs_tot[i][r] = 0.f;

  // virtual step v = nt*8 + ks: A cols ks*64, B rows nbase+nt*128, cols ks*64
  auto STAGE = [&](int v, int st) {
    int nt = v >> 3, kt = (v & 7) * 64;
    const u8* ga = gA + kt;
    const u8* gb = gBb + (size_t)(nt * 128) * 1024 + kt;
    gld_lds16(ga,      &smem[st * 8192 + ldsOff]);
    gld_lds16(ga + 32, &smem[st * 8192 + 4096 + ldsOff]);
    gld_lds16(gb,      &smem[24576 + st * 8192 + ldsOff]);
    gld_lds16(gb + 32, &smem[24576 + st * 8192 + 4096 + ldsOff]);
  };

  STAGE(0, 0);
  STAGE(1, 1);
  __builtin_amdgcn_sched_barrier(0);
  asm volatile("s_waitcnt vmcnt(4)");
  bar();

  int s = 0;
  #pragma unroll 1
  for (int v = 0; v < 64; ++v) {
    if (v + 2 < 64) STAGE(v + 2, (s == 0) ? 2 : s - 1);
    const int sb = s * 8192;
    long af[4][2], bf[4][2];
    #pragma unroll
    for (int i = 0; i < 4; ++i) {
      #pragma unroll
      for (int g = 0; g < 2; ++g) {
        af[i][g] = *(const long*)&smem[sb + g * 4096 + aoff[i]];
        bf[i][g] = *(const long*)&smem[24576 + sb + g * 4096 + boff[i]];
      }
    }
    #pragma unroll
    for (int i = 0; i < 4; ++i)
      #pragma unroll
      for (int j = 0; j < 4; ++j) {
        acc[i][j] = __builtin_amdgcn_mfma_f32_16x16x32_fp8_fp8(
            af[i][0], bf[j][0], acc[i][j], 0, 0, 0);
        acc[i][j] = __builtin_amdgcn_mfma_f32_16x16x32_fp8_fp8(
            af[i][1], bf[j][1], acc[i][j], 0, 0, 0);
      }

    if ((v & 7) == 7) {
      // ---- nt boundary: epilogue for this n-tile (stages stay in flight) --
      int n0e = nbase + (v >> 3) * 128;
      bar();  // prev epilogue's bounce reads are done (cadence: >=1 bar ago)
      #pragma unroll
      for (int i = 0; i < 4; ++i) {
        int lm = wm * 64 + i * 16 + quad * 4;
        #pragma unroll
        for (int j = 0; j < 4; ++j) {
          int ln = wn * 64 + j * 16 + li;
          #pragma unroll
          for (int r = 0; r < 4; ++r) {
            float e = fminf(__expf(acc[i][j][r]), 448.f);
            smem[49152 + (lm + r) * 144 + ln] = f2f8(e);
            rs_tot[i][r] += e;
          }
          acc[i][j] = zero;
        }
      }
      __builtin_amdgcn_sched_barrier(0);
      asm volatile("s_waitcnt lgkmcnt(0)");
      bar();
      {
        int row = t >> 1, half = t & 1;
        const u8* src = &smem[49152 + row * 144 + half * 64];
        u8* dst = outp + (size_t)(m0 + row) * 4096 + n0e + half * 64;
        #pragma unroll
        for (int cc = 0; cc < 4; ++cc)
          *(uint4*)(dst + cc * 16) = *(const uint4*)(src + cc * 16);
      }
      bar();  // protect bounce before next epilogue's writes
      if (v + 1 < 64) {
        __builtin_amdgcn_sched_barrier(0);
        // outstanding: stage v+1 (4) + stage v+2 (4) + 4 epilogue stores
        // -> vmcnt(8) leaves v+2 loads + stores, guarantees v+1 landed.
        asm volatile("s_waitcnt vmcnt(8)");
        bar();
      }
    } else {
      __builtin_amdgcn_sched_barrier(0);
      if (v + 2 < 64) asm volatile("s_waitcnt vmcnt(4)");
      else            asm volatile("s_waitcnt vmcnt(0)");
      bar();
    }
    s = (s == 2) ? 0 : s + 1;
  }

  // ---- deferred rowsum reduction + atomics ----
  #pragma unroll
  for (int i = 0; i < 4; ++i) {
    int lm = wm * 64 + i * 16 + quad * 4;
    #pragma unroll
    for (int r = 0; r < 4; ++r) {
      float rv = rs_tot[i][r];
      rv += __shfl_xor(rv, 1);
      rv += __shfl_xor(rv, 2);
      rv += __shfl_xor(rv, 4);
      rv += __shfl_xor(rv, 8);
      if (li == 0) atomicAdd(&rsF[m0 + lm + r], rv);
    }
  }
}

extern "C" void kernel_launch(void* const* d_in, const int* in_sizes, int n_in,
                              void* d_out, int out_size, void* d_ws, size_t ws_size,
                              hipStream_t stream) {
  (void)in_sizes; (void)n_in; (void)out_size; (void)ws_size;
  const float* x      = (const float*)d_in[0];
  const float* gamma  = (const float*)d_in[1];
  const float* beta   = (const float*)d_in[2];
  const float* w_qkv  = (const float*)d_in[3];
  const float* b_qkv  = (const float*)d_in[4];
  const float* w_proj = (const float*)d_in[5];
  const float* b_proj = (const float*)d_in[6];
  float* out = (float*)d_out;

  const int C = 512, N = 4096;
  const size_t NC = (size_t)N * C;
  const float scale = 0.21022410381342863f;  // 512^-0.25

  char* ws = (char*)d_ws;
  size_t off = 0;
  auto alloc = [&](size_t bytes) -> char* {
    char* p = ws + off; off += (bytes + 255) & ~(size_t)255; return p;
  };
  u16*   wq_bf  = (u16*)alloc((size_t)1536 * 512 * 2);
  u16*   wp_bf  = (u16*)alloc((size_t)512 * 512 * 2);
  float* stats  = (float*)alloc(128 * 2 * 4);
  float* rowsum = (float*)alloc((size_t)4 * N * 4);
  u16*   xnT    = (u16*)alloc((size_t)4 * NC * 2);      // [b][n][c] bf16
  u8*    qkT    = (u8*)alloc((size_t)4 * N * 1024);     // [b][i][o] fp8, o<1024
  u8*    vbf    = (u8*)alloc((size_t)4 * 512 * 4096);   // [b][c][j] fp8
  u16*   ao     = (u16*)alloc((size_t)4 * NC * 2);      // [b][i][c] bf16
  u8*    E      = (u8*)alloc((size_t)4 * N * N);        // [b][i][j] fp8

  cvt_weights<<<3072, 256, 0, stream>>>(w_qkv, w_proj, wq_bf, wp_bf);
  gn_stats<<<128, 256, 0, stream>>>(x, stats);
  gn_norm_t<<<dim3(64, 8, 4), 256, 0, stream>>>(x, stats, gamma, beta, xnT);
  hipMemsetAsync(rowsum, 0, (size_t)4 * N * 4, stream);

  // qkT[b][i][o] = fp8((sum_c xnT[b][i][c]*wq[o][c] + b_qkv[o]) * scale)
  gemm_nt<4><<<dim3(8, 32, 4), 256, 0, stream>>>(
      xnT, wq_bf, 512, 512, 512, b_qkv, nullptr, scale,
      nullptr, qkT, 1024, NC, 0, (size_t)N * 1024);
  // vbf[b][c][j] = fp8(sum_k wq[1024+c][k]*xnT[b][j][k] + b_qkv[1024+c])
  gemm_nt<5><<<dim3(32, 4, 4), 256, 0, stream>>>(
      wq_bf + (size_t)1024 * 512, xnT, 512, 512, 512, b_qkv + 1024, nullptr,
      0.f, nullptr, vbf, 4096, 0, NC, (size_t)512 * 4096);
  // E[b][i][j] = fp8(exp(S)), rowsum[b][i] += partials (strip kernel,
  // 512 long-lived blocks, 64 steps each)
  qk_strip<<<dim3(4, 32, 4), 256, 0, stream>>>(qkT, qkT + 512, rowsum, E);
  // ao[b][i][c] = bf16((sum_j E*v) * rcp(rowsum[b][i]))  (BK=64, 64 steps)
  gemm_nt8<6, 0><<<dim3(4, 32, 4), 256, 0, stream>>>(
      E, vbf, 4096, 4096, 4096, rowsum, nullptr,
      ao, 512, (size_t)N * N, (size_t)512 * 4096, NC);
  // out[b][o][n] = sum_c wp[o][c]*ao[b][n][c] + b_proj[o] + x[b][o][n]
  gemm_nt<3><<<dim3(32, 4, 4), 256, 0, stream>>>(
      wp_bf, ao, 512, 512, 512, b_proj, x, 0.f,
      out, nullptr, 4096, 0, NC, NC);
}

// Round 10
// 366.160 us; speedup vs baseline: 1.0737x; 1.0346x over previous
//
#include <hip/hip_runtime.h>
#include <hip/hip_fp8.h>
#include <stdint.h>

typedef unsigned short u16;
typedef unsigned char u8;
typedef __bf16 bf16x8 __attribute__((ext_vector_type(8)));
typedef float f32x4 __attribute__((ext_vector_type(4)));

__device__ __forceinline__ u16 f2bf(float f) {
  union { float f; unsigned u; } v; v.f = f;
  return (u16)((v.u + 0x7FFFu + ((v.u >> 16) & 1u)) >> 16);
}
__device__ __forceinline__ u8 f2f8(float f) {
  __hip_fp8_e4m3 h(f);
  return (u8)h.__x;
}

// async 16B global -> LDS (wave-uniform LDS base; HW writes base + lane*16)
__device__ __forceinline__ void gld_lds16(const void* g, void* l) {
  uint32_t lo = (uint32_t)(uintptr_t)l;
  lo = __builtin_amdgcn_readfirstlane(lo);
  auto* lp = (__attribute__((address_space(3))) uint32_t*)(uintptr_t)lo;
  auto* gp = (const __attribute__((address_space(1))) uint32_t*)(uintptr_t)g;
  __builtin_amdgcn_global_load_lds(gp, lp, 16, 0, 0);
}

// clobber-free barrier, fenced so no memory op crosses at schedule time.
__device__ __forceinline__ void bar() {
  __builtin_amdgcn_sched_barrier(0);
  __builtin_amdgcn_s_barrier();
  __builtin_amdgcn_sched_barrier(0);
}

// ---------------- weight fp32 -> bf16 ----------------
__global__ __launch_bounds__(256) void cvt_weights(
    const float* __restrict__ wq, const float* __restrict__ wp,
    u16* __restrict__ oq, u16* __restrict__ op) {
  int i = blockIdx.x * 256 + threadIdx.x;
  if (i < 1536 * 512) oq[i] = f2bf(wq[i]);
  if (i < 512 * 512)  op[i] = f2bf(wp[i]);
}

// ---------------- group norm stats ----------------
__global__ __launch_bounds__(256) void gn_stats(const float* __restrict__ x,
                                                float* __restrict__ stats) {
  int bg = blockIdx.x;  // 0..127
  const float* p = x + (size_t)bg * 65536;
  float s = 0.f, sq = 0.f;
  for (int i = threadIdx.x * 4; i < 65536; i += 1024) {
    float4 v = *(const float4*)(p + i);
    s += v.x + v.y + v.z + v.w;
    sq += v.x * v.x + v.y * v.y + v.z * v.z + v.w * v.w;
  }
  int lane = threadIdx.x & 63, w = threadIdx.x >> 6;
  for (int off = 32; off; off >>= 1) {
    s += __shfl_down(s, off);
    sq += __shfl_down(sq, off);
  }
  __shared__ float ls[4], lq[4];
  if (lane == 0) { ls[w] = s; lq[w] = sq; }
  __syncthreads();
  if (threadIdx.x == 0) {
    float S = ls[0] + ls[1] + ls[2] + ls[3];
    float Q = lq[0] + lq[1] + lq[2] + lq[3];
    float mean = S * (1.f / 65536.f);
    float var = Q * (1.f / 65536.f) - mean * mean;
    stats[bg * 2] = mean;
    stats[bg * 2 + 1] = rsqrtf(var + 1e-6f);
  }
}

// ---------------- group norm + transpose: x[b][c][n] -> xnT[b][n][c] bf16 ----
__global__ __launch_bounds__(256) void gn_norm_t(const float* __restrict__ x,
    const float* __restrict__ stats, const float* __restrict__ gamma,
    const float* __restrict__ beta, u16* __restrict__ xnT) {
  __shared__ u16 tile[64][72];
  int b = blockIdx.z;
  int c0 = blockIdx.y * 64, n0 = blockIdx.x * 64;
  int t = threadIdx.x;
  int cl = t >> 2, ng = (t & 3) * 16;
  int c = c0 + cl;
  float mean = stats[(b * 32 + (c >> 4)) * 2];
  float rstd = stats[(b * 32 + (c >> 4)) * 2 + 1];
  float a = gamma[c] * rstd;
  float b2 = beta[c] - mean * a;
  const float* src = x + ((size_t)b * 512 + c) * 4096 + n0 + ng;
  u16 e[16];
  #pragma unroll
  for (int q = 0; q < 4; ++q) {
    float4 v = *(const float4*)(src + q * 4);
    e[q * 4 + 0] = f2bf(v.x * a + b2);
    e[q * 4 + 1] = f2bf(v.y * a + b2);
    e[q * 4 + 2] = f2bf(v.z * a + b2);
    e[q * 4 + 3] = f2bf(v.w * a + b2);
  }
  #pragma unroll
  for (int j = 0; j < 16; ++j) tile[ng + j][cl] = e[j];
  __syncthreads();
  int nl = t >> 2, cg = (t & 3) * 16;
  uint4 w0 = *(const uint4*)&tile[nl][cg];
  uint4 w1 = *(const uint4*)&tile[nl][cg + 8];
  u16* dst = xnT + ((size_t)b * 4096 + n0 + nl) * 512 + c0 + cg;
  *(uint4*)dst = w0;
  *(uint4*)(dst + 8) = w1;
}

// ------------- bf16 NT GEMM: C[m][n] = sum_k A[m*lda+k]*B[n*ldb+k] --------
// 128x128 tile, BK=32, dbuf LDS + global_load_lds.
// EPI: 3 = fp32 out + bias[m] + resid (proj)
//      4 = fp8 out, (acc+bias[n])*scale  (qk: m=spatial, n=channel)
//      5 = fp8 out, acc+bias[m]          (v:  m=channel, n=spatial)
template<int EPI>
__global__ __launch_bounds__(256) void gemm_nt(
    const u16* __restrict__ A, const u16* __restrict__ B,
    int lda, int ldb, int K,
    const float* __restrict__ bias, const float* __restrict__ resid,
    float scale, float* __restrict__ outF, void* __restrict__ outBv, int ldo,
    size_t azs, size_t bzs, size_t ozs) {
  __shared__ __align__(16) u16 smem[16384];
  const size_t z = blockIdx.z;
  A += z * azs; B += z * bzs;
  const int t = threadIdx.x;
  const int wave = t >> 6, lane = t & 63;
  const int wm = wave >> 1, wn = wave & 1;
  const int quad = lane >> 4, li = lane & 15;
  const int m0 = blockIdx.y * 128, n0 = blockIdx.x * 128;

  const int srow = lane >> 2;
  const int scol = (lane & 3) * 8;
  const u16* gA[2];
  const u16* gB[2];
  int ldsOff[2];
  #pragma unroll
  for (int r = 0; r < 2; ++r) {
    int rb = wave + 4 * r;
    gA[r] = A + (size_t)(m0 + rb * 16 + srow) * lda + scol;
    gB[r] = B + (size_t)(n0 + rb * 16 + srow) * ldb + scol;
    ldsOff[r] = rb * 512;
  }

  f32x4 zero = {0.f, 0.f, 0.f, 0.f};
  f32x4 acc[4][4];
  #pragma unroll
  for (int i = 0; i < 4; ++i)
    #pragma unroll
    for (int j = 0; j < 4; ++j) acc[i][j] = zero;

  #pragma unroll
  for (int r = 0; r < 2; ++r) {
    gld_lds16(gA[r], &smem[ldsOff[r]]);
    gld_lds16(gB[r], &smem[8192 + ldsOff[r]]);
  }
  __syncthreads();

  for (int kt = 0; kt < K; kt += 32) {
    const int s = (kt >> 5) & 1;
    if (kt + 32 < K) {
      const int ns = s ^ 1;
      #pragma unroll
      for (int r = 0; r < 2; ++r) {
        gld_lds16(gA[r] + kt + 32, &smem[ns * 4096 + ldsOff[r]]);
        gld_lds16(gB[r] + kt + 32, &smem[8192 + ns * 4096 + ldsOff[r]]);
      }
    }
    bf16x8 af[4], bf[4];
    #pragma unroll
    for (int i = 0; i < 4; ++i) {
      af[i] = *(const bf16x8*)&smem[s * 4096 +
               (wm * 64 + i * 16 + li) * 32 + quad * 8];
      bf[i] = *(const bf16x8*)&smem[8192 + s * 4096 +
               (wn * 64 + i * 16 + li) * 32 + quad * 8];
    }
    #pragma unroll
    for (int i = 0; i < 4; ++i)
      #pragma unroll
      for (int j = 0; j < 4; ++j)
        acc[i][j] = __builtin_amdgcn_mfma_f32_16x16x32_bf16(
            af[i], bf[j], acc[i][j], 0, 0, 0);
    __syncthreads();
  }

  if (EPI == 3) {
    outF += z * ozs; resid += z * ozs;
    #pragma unroll
    for (int i = 0; i < 4; ++i)
      #pragma unroll
      for (int j = 0; j < 4; ++j) {
        int mB = m0 + wm * 64 + i * 16 + quad * 4;
        int n = n0 + wn * 64 + j * 16 + li;
        #pragma unroll
        for (int r = 0; r < 4; ++r) {
          int m = mB + r;
          float v = acc[i][j][r] + bias[m] + resid[(size_t)m * ldo + n];
          outF[(size_t)m * ldo + n] = v;
        }
      }
    return;
  }

  // fp8 outputs (EPI 4/5): bounce through LDS, coalesced stores
  u8* out8 = (u8*)outBv + z * ozs;
  u8* bnc = (u8*)smem;
  #pragma unroll
  for (int i = 0; i < 4; ++i) {
    int lm = wm * 64 + i * 16 + quad * 4;
    #pragma unroll
    for (int j = 0; j < 4; ++j) {
      int ln = wn * 64 + j * 16 + li;
      #pragma unroll
      for (int r = 0; r < 4; ++r) {
        float v = acc[i][j][r];
        u8 o;
        if (EPI == 4) o = f2f8((v + bias[n0 + ln]) * scale);
        else          o = f2f8(v + bias[m0 + lm + r]);
        bnc[(lm + r) * 144 + ln] = o;
      }
    }
  }
  __syncthreads();
  {
    int row = t >> 1, half = t & 1;
    const u8* src = &bnc[row * 144 + half * 64];
    u8* dst = out8 + (size_t)(m0 + row) * ldo + n0 + half * 64;
    #pragma unroll
    for (int cc = 0; cc < 4; ++cc)
      *(uint4*)(dst + cc * 16) = *(const uint4*)(src + cc * 16);
  }
}

// ------------- PV fp8 NT GEMM (EPI6): 128x128, BK=64, 3-stage -------------
// (R7-proven: BK=64 halved PV's step count, ~120 -> ~82 us.)
template<int EPI, int SWZ>
__global__ __launch_bounds__(256) void gemm_nt8(
    const u8* __restrict__ A, const u8* __restrict__ B,
    int lda, int ldb, int K,
    const float* __restrict__ rsum, float* __restrict__ outF,
    void* __restrict__ outBv, int ldo,
    size_t azs, size_t bzs, size_t ozs) {
  __shared__ __align__(16) u8 smem[49152];
  const size_t z = blockIdx.z;
  A += z * azs; B += z * bzs;
  int bx = blockIdx.x, by = blockIdx.y;
  if (SWZ) {
    int lin = by * 32 + bx;
    int tt = lin >> 8, w = lin & 255;
    by = (tt >> 1) * 16 + (w >> 4);
    bx = (tt & 1) * 16 + (w & 15);
  }
  const int t = threadIdx.x;
  const int wave = t >> 6, lane = t & 63;
  const int wm = wave >> 1, wn = wave & 1;
  const int quad = lane >> 4, li = lane & 15;
  const int m0 = by * 128, n0 = bx * 128;

  const int us = lane ^ ((lane >> 3) & 7);
  const int srow = (us >> 1) & 31;
  const int shalf = us & 1;
  const u8* gA = A + (size_t)(m0 + wave * 32 + srow) * lda + shalf * 16;
  const u8* gB = B + (size_t)(n0 + wave * 32 + srow) * ldb + shalf * 16;
  const int ldsOff = wave * 1024;

  const int h = quad >> 1, qlo = (quad & 1) * 8;
  int aoff[4], boff[4];
  #pragma unroll
  for (int i = 0; i < 4; ++i) {
    int r5 = (i & 1) * 16 + li;
    int p = (2 * r5 + h) ^ ((r5 >> 2) & 7);
    aoff[i] = (wm * 2 + (i >> 1)) * 1024 + p * 16 + qlo;
    boff[i] = (wn * 2 + (i >> 1)) * 1024 + p * 16 + qlo;
  }

  f32x4 zero = {0.f, 0.f, 0.f, 0.f};
  f32x4 acc[4][4];
  #pragma unroll
  for (int i = 0; i < 4; ++i)
    #pragma unroll
    for (int j = 0; j < 4; ++j) acc[i][j] = zero;

  #pragma unroll
  for (int p = 0; p < 2; ++p) {
    gld_lds16(gA + p * 64,      &smem[p * 8192 + ldsOff]);
    gld_lds16(gA + p * 64 + 32, &smem[p * 8192 + 4096 + ldsOff]);
    gld_lds16(gB + p * 64,      &smem[24576 + p * 8192 + ldsOff]);
    gld_lds16(gB + p * 64 + 32, &smem[24576 + p * 8192 + 4096 + ldsOff]);
  }
  __builtin_amdgcn_sched_barrier(0);
  asm volatile("s_waitcnt vmcnt(4)");
  bar();

  int s = 0;
  for (int kt = 0; kt < K; kt += 64) {
    if (kt + 128 < K) {
      const int ns = (s == 0) ? 2 : s - 1;  // (s+2)%3
      gld_lds16(gA + kt + 128,      &smem[ns * 8192 + ldsOff]);
      gld_lds16(gA + kt + 128 + 32, &smem[ns * 8192 + 4096 + ldsOff]);
      gld_lds16(gB + kt + 128,      &smem[24576 + ns * 8192 + ldsOff]);
      gld_lds16(gB + kt + 128 + 32, &smem[24576 + ns * 8192 + 4096 + ldsOff]);
    }
    const int sb = s * 8192;
    long af[4][2], bf[4][2];
    #pragma unroll
    for (int i = 0; i < 4; ++i) {
      #pragma unroll
      for (int g = 0; g < 2; ++g) {
        af[i][g] = *(const long*)&smem[sb + g * 4096 + aoff[i]];
        bf[i][g] = *(const long*)&smem[24576 + sb + g * 4096 + boff[i]];
      }
    }
    #pragma unroll
    for (int i = 0; i < 4; ++i)
      #pragma unroll
      for (int j = 0; j < 4; ++j) {
        acc[i][j] = __builtin_amdgcn_mfma_f32_16x16x32_fp8_fp8(
            af[i][0], bf[j][0], acc[i][j], 0, 0, 0);
        acc[i][j] = __builtin_amdgcn_mfma_f32_16x16x32_fp8_fp8(
            af[i][1], bf[j][1], acc[i][j], 0, 0, 0);
      }
    if (kt + 64 < K) {
      __builtin_amdgcn_sched_barrier(0);
      if (kt + 128 < K) asm volatile("s_waitcnt vmcnt(4)");
      else              asm volatile("s_waitcnt vmcnt(0)");
      bar();
    }
    s = (s == 2) ? 0 : s + 1;
  }
  __syncthreads();

  {  // EPI 6: PV epilogue
    const float* rsF = rsum + z * 4096;
    u16* outp = (u16*)outBv + z * ozs;
    u16* b16 = (u16*)smem;
    #pragma unroll
    for (int i = 0; i < 4; ++i) {
      int lm = wm * 64 + i * 16 + quad * 4;
      float rinv[4];
      #pragma unroll
      for (int r = 0; r < 4; ++r)
        rinv[r] = __builtin_amdgcn_rcpf(rsF[m0 + lm + r]);
      #pragma unroll
      for (int j = 0; j < 4; ++j) {
        int ln = wn * 64 + j * 16 + li;
        #pragma unroll
        for (int r = 0; r < 4; ++r)
          b16[(lm + r) * 136 + ln] = f2bf(acc[i][j][r] * rinv[r]);
      }
    }
    __syncthreads();
    int row = t >> 1, half = t & 1;
    const u16* src = &b16[row * 136 + half * 64];
    u16* dst = outp + (size_t)(m0 + row) * ldo + n0 + half * 64;
    #pragma unroll
    for (int cc = 0; cc < 8; ++cc)
      *(uint4*)(dst + cc * 8) = *(const uint4*)(src + cc * 8);
  }
}

// ------------- QK^T 256x128-tile, 8-wave fp8 GEMM + exp + rowsum ----------
// Last untried cell in the 9-round A/B matrix: double MFMA-per-barrier-
// per-CU while RAISING waves/SIMD.  8 waves (4m x 2n), each wave = the
// R7-proven 64x64 step body (32 MFMA, acc 4x4, BK=64 two panels).  LDS
// 72KB -> 2 blocks/CU = 16 waves/CU = 4 waves/SIMD (vs R7's 3);
// __launch_bounds__(512,4) pins VGPR <= 128 to avoid qk256's occupancy
// cliff (it compiled to 132 VGPR -> 2 waves/SIMD -> 10% occupancy).
// 3-stage counted pipeline; same swizzle; same panel0->panel1 k-ascending
// accumulation order -> bit-identical E vs R7.
__global__ __launch_bounds__(512, 4) void qk8w(
    const u8* __restrict__ A, const u8* __restrict__ B,
    float* __restrict__ rowsum, u8* __restrict__ outE) {
  // LDS: A stages s*16384 [0,49152): panel g at g*8192, region w (0..7)*1024
  //      B stages 49152+s*8192 [49152,73728): panel g at g*4096, region
  //      (w&3)*1024.  Epilogue bounce u8[256][144]=36864 overlays [0,..).
  __shared__ __align__(16) u8 smem[73728];
  const int lda = 1024, K = 512;
  const size_t z = blockIdx.z;
  A += (size_t)z * 4096 * 1024;
  B += (size_t)z * 4096 * 1024;
  float* rsF = rowsum + (size_t)z * 4096;
  u8* outp = outE + (size_t)z * 4096 * 4096;

  const int t = threadIdx.x;
  const int w = t >> 6, lane = t & 63;
  const int wm = w >> 1, wn = w & 1;   // wave grid 4 (M) x 2 (N)
  const int quad = lane >> 4, li = lane & 15;
  const int m0 = blockIdx.y * 256, n0 = blockIdx.x * 128;

  // staging (pre-swizzled global source, linear LDS dest)
  const int us = lane ^ ((lane >> 3) & 7);
  const int srow = (us >> 1) & 31;
  const int shalf = us & 1;
  const u8* gA = A + (size_t)(m0 + w * 32 + srow) * lda + shalf * 16;
  const bool doB = w < 4;
  const u8* gB = B + (size_t)(n0 + (w & 3) * 32 + srow) * lda + shalf * 16;

  // frag read offsets: p = (2*r5+h) ^ ((r5>>2)&7) within a 1KB region
  const int h = quad >> 1, qlo = (quad & 1) * 8;
  int aoff[4], boff[4];
  #pragma unroll
  for (int i = 0; i < 4; ++i) {
    int r5 = (i & 1) * 16 + li;
    int p = (2 * r5 + h) ^ ((r5 >> 2) & 7);
    aoff[i] = (wm * 2 + (i >> 1)) * 1024 + p * 16 + qlo;
    boff[i] = (wn * 2 + (i >> 1)) * 1024 + p * 16 + qlo;
  }

  f32x4 zero = {0.f, 0.f, 0.f, 0.f};
  f32x4 acc[4][4];
  #pragma unroll
  for (int i = 0; i < 4; ++i)
    #pragma unroll
    for (int j = 0; j < 4; ++j) acc[i][j] = zero;

  // stage one BK=64 step (A: 2 glds all waves; B: 2 glds waves 0-3)
  auto STAGE = [&](int kt, int st) {
    int sA = st * 16384, sB = 49152 + st * 8192;
    #pragma unroll
    for (int g = 0; g < 2; ++g) {
      gld_lds16(gA + kt + g * 32, &smem[sA + g * 8192 + w * 1024]);
      if (doB)
        gld_lds16(gB + kt + g * 32, &smem[sB + g * 4096 + (w & 3) * 1024]);
    }
  };

  STAGE(0, 0);
  STAGE(64, 1);
  __builtin_amdgcn_sched_barrier(0);
  if (doB) asm volatile("s_waitcnt vmcnt(4)");
  else     asm volatile("s_waitcnt vmcnt(2)");
  bar();

  int s = 0;
  for (int kt = 0; kt < K; kt += 64) {
    if (kt + 128 < K) STAGE(kt + 128, (s == 0) ? 2 : s - 1);
    const int sA = s * 16384, sB = 49152 + s * 8192;
    long af[4][2], bf[4][2];
    #pragma unroll
    for (int i = 0; i < 4; ++i) {
      #pragma unroll
      for (int g = 0; g < 2; ++g) {
        af[i][g] = *(const long*)&smem[sA + g * 8192 + aoff[i]];
        bf[i][g] = *(const long*)&smem[sB + g * 4096 + boff[i]];
      }
    }
    #pragma unroll
    for (int i = 0; i < 4; ++i)
      #pragma unroll
      for (int j = 0; j < 4; ++j) {
        acc[i][j] = __builtin_amdgcn_mfma_f32_16x16x32_fp8_fp8(
            af[i][0], bf[j][0], acc[i][j], 0, 0, 0);
        acc[i][j] = __builtin_amdgcn_mfma_f32_16x16x32_fp8_fp8(
            af[i][1], bf[j][1], acc[i][j], 0, 0, 0);
      }
    if (kt + 64 < K) {
      __builtin_amdgcn_sched_barrier(0);
      if (kt + 128 < K) {
        if (doB) asm volatile("s_waitcnt vmcnt(4)");
        else     asm volatile("s_waitcnt vmcnt(2)");
      } else {
        asm volatile("s_waitcnt vmcnt(0)");
      }
      bar();
    }
    s = (s == 2) ? 0 : s + 1;
  }
  __syncthreads();  // all waves done reading stages before bounce overlay

  // epilogue: exp + clamp, rowsum atomics, fp8 bounce + coalesced stores
  #pragma unroll
  for (int i = 0; i < 4; ++i) {
    int lm = wm * 64 + i * 16 + quad * 4;   // rows 0..255
    float rs[4] = {0.f, 0.f, 0.f, 0.f};
    #pragma unroll
    for (int j = 0; j < 4; ++j) {
      int ln = wn * 64 + j * 16 + li;       // cols 0..127
      #pragma unroll
      for (int r = 0; r < 4; ++r) {
        float e = fminf(__expf(acc[i][j][r]), 448.f);
        smem[(lm + r) * 144 + ln] = f2f8(e);
        rs[r] += e;
      }
    }
    #pragma unroll
    for (int r = 0; r < 4; ++r) {
      rs[r] += __shfl_xor(rs[r], 1);
      rs[r] += __shfl_xor(rs[r], 2);
      rs[r] += __shfl_xor(rs[r], 4);
      rs[r] += __shfl_xor(rs[r], 8);
    }
    if (li == 0) {
      #pragma unroll
      for (int r = 0; r < 4; ++r) atomicAdd(&rsF[m0 + lm + r], rs[r]);
    }
  }
  __syncthreads();
  {
    int row = t >> 1, half = t & 1;   // 512 threads: 256 rows x 2 halves
    const u8* src = &smem[row * 144 + half * 64];
    u8* dst = outp + (size_t)(m0 + row) * 4096 + n0 + half * 64;
    #pragma unroll
    for (int cc = 0; cc < 4; ++cc)
      *(uint4*)(dst + cc * 16) = *(const uint4*)(src + cc * 16);
  }
}

extern "C" void kernel_launch(void* const* d_in, const int* in_sizes, int n_in,
                              void* d_out, int out_size, void* d_ws, size_t ws_size,
                              hipStream_t stream) {
  (void)in_sizes; (void)n_in; (void)out_size; (void)ws_size;
  const float* x      = (const float*)d_in[0];
  const float* gamma  = (const float*)d_in[1];
  const float* beta   = (const float*)d_in[2];
  const float* w_qkv  = (const float*)d_in[3];
  const float* b_qkv  = (const float*)d_in[4];
  const float* w_proj = (const float*)d_in[5];
  const float* b_proj = (const float*)d_in[6];
  float* out = (float*)d_out;

  const int C = 512, N = 4096;
  const size_t NC = (size_t)N * C;
  const float scale = 0.21022410381342863f;  // 512^-0.25

  char* ws = (char*)d_ws;
  size_t off = 0;
  auto alloc = [&](size_t bytes) -> char* {
    char* p = ws + off; off += (bytes + 255) & ~(size_t)255; return p;
  };
  u16*   wq_bf  = (u16*)alloc((size_t)1536 * 512 * 2);
  u16*   wp_bf  = (u16*)alloc((size_t)512 * 512 * 2);
  float* stats  = (float*)alloc(128 * 2 * 4);
  float* rowsum = (float*)alloc((size_t)4 * N * 4);
  u16*   xnT    = (u16*)alloc((size_t)4 * NC * 2);      // [b][n][c] bf16
  u8*    qkT    = (u8*)alloc((size_t)4 * N * 1024);     // [b][i][o] fp8, o<1024
  u8*    vbf    = (u8*)alloc((size_t)4 * 512 * 4096);   // [b][c][j] fp8
  u16*   ao     = (u16*)alloc((size_t)4 * NC * 2);      // [b][i][c] bf16
  u8*    E      = (u8*)alloc((size_t)4 * N * N);        // [b][i][j] fp8

  cvt_weights<<<3072, 256, 0, stream>>>(w_qkv, w_proj, wq_bf, wp_bf);
  gn_stats<<<128, 256, 0, stream>>>(x, stats);
  gn_norm_t<<<dim3(64, 8, 4), 256, 0, stream>>>(x, stats, gamma, beta, xnT);
  hipMemsetAsync(rowsum, 0, (size_t)4 * N * 4, stream);

  // qkT[b][i][o] = fp8((sum_c xnT[b][i][c]*wq[o][c] + b_qkv[o]) * scale)
  gemm_nt<4><<<dim3(8, 32, 4), 256, 0, stream>>>(
      xnT, wq_bf, 512, 512, 512, b_qkv, nullptr, scale,
      nullptr, qkT, 1024, NC, 0, (size_t)N * 1024);
  // vbf[b][c][j] = fp8(sum_k wq[1024+c][k]*xnT[b][j][k] + b_qkv[1024+c])
  gemm_nt<5><<<dim3(32, 4, 4), 256, 0, stream>>>(
      wq_bf + (size_t)1024 * 512, xnT, 512, 512, 512, b_qkv + 1024, nullptr,
      0.f, nullptr, vbf, 4096, 0, NC, (size_t)512 * 4096);
  // E[b][i][j] = fp8(exp(S)), rowsum[b][i] += partials (256x128, 8 waves,
  // 4 waves/SIMD)
  qk8w<<<dim3(32, 16, 4), 512, 0, stream>>>(qkT, qkT + 512, rowsum, E);
  // ao[b][i][c] = bf16((sum_j E*v) * rcp(rowsum[b][i]))  (BK=64, 64 steps)
  gemm_nt8<6, 0><<<dim3(4, 32, 4), 256, 0, stream>>>(
      E, vbf, 4096, 4096, 4096, rowsum, nullptr,
      ao, 512, (size_t)N * N, (size_t)512 * 4096, NC);
  // out[b][o][n] = sum_c wp[o][c]*ao[b][n][c] + b_proj[o] + x[b][o][n]
  gemm_nt<3><<<dim3(32, 4, 4), 256, 0, stream>>>(
      wp_bf, ao, 512, 512, 512, b_proj, x, 0.f,
      out, nullptr, 4096, 0, NC, NC);
}

// Round 11
// 361.075 us; speedup vs baseline: 1.0888x; 1.0141x over previous
//
#include <hip/hip_runtime.h>
#include <hip/hip_fp8.h>
#include <stdint.h>

typedef unsigned short u16;
typedef unsigned char u8;
typedef __bf16 bf16x8 __attribute__((ext_vector_type(8)));
typedef float f32x4 __attribute__((ext_vector_type(4)));

__device__ __forceinline__ u16 f2bf(float f) {
  union { float f; unsigned u; } v; v.f = f;
  return (u16)((v.u + 0x7FFFu + ((v.u >> 16) & 1u)) >> 16);
}
__device__ __forceinline__ u8 f2f8(float f) {
  __hip_fp8_e4m3 h(f);
  return (u8)h.__x;
}

// async 16B global -> LDS (wave-uniform LDS base; HW writes base + lane*16)
__device__ __forceinline__ void gld_lds16(const void* g, void* l) {
  uint32_t lo = (uint32_t)(uintptr_t)l;
  lo = __builtin_amdgcn_readfirstlane(lo);
  auto* lp = (__attribute__((address_space(3))) uint32_t*)(uintptr_t)lo;
  auto* gp = (const __attribute__((address_space(1))) uint32_t*)(uintptr_t)g;
  __builtin_amdgcn_global_load_lds(gp, lp, 16, 0, 0);
}

// clobber-free barrier, fenced so no memory op crosses at schedule time.
__device__ __forceinline__ void bar() {
  __builtin_amdgcn_sched_barrier(0);
  __builtin_amdgcn_s_barrier();
  __builtin_amdgcn_sched_barrier(0);
}

// ---------------- weight fp32 -> bf16 ----------------
__global__ __launch_bounds__(256) void cvt_weights(
    const float* __restrict__ wq, const float* __restrict__ wp,
    u16* __restrict__ oq, u16* __restrict__ op) {
  int i = blockIdx.x * 256 + threadIdx.x;
  if (i < 1536 * 512) oq[i] = f2bf(wq[i]);
  if (i < 512 * 512)  op[i] = f2bf(wp[i]);
}

// ---------------- group norm stats ----------------
__global__ __launch_bounds__(256) void gn_stats(const float* __restrict__ x,
                                                float* __restrict__ stats) {
  int bg = blockIdx.x;  // 0..127
  const float* p = x + (size_t)bg * 65536;
  float s = 0.f, sq = 0.f;
  for (int i = threadIdx.x * 4; i < 65536; i += 1024) {
    float4 v = *(const float4*)(p + i);
    s += v.x + v.y + v.z + v.w;
    sq += v.x * v.x + v.y * v.y + v.z * v.z + v.w * v.w;
  }
  int lane = threadIdx.x & 63, w = threadIdx.x >> 6;
  for (int off = 32; off; off >>= 1) {
    s += __shfl_down(s, off);
    sq += __shfl_down(sq, off);
  }
  __shared__ float ls[4], lq[4];
  if (lane == 0) { ls[w] = s; lq[w] = sq; }
  __syncthreads();
  if (threadIdx.x == 0) {
    float S = ls[0] + ls[1] + ls[2] + ls[3];
    float Q = lq[0] + lq[1] + lq[2] + lq[3];
    float mean = S * (1.f / 65536.f);
    float var = Q * (1.f / 65536.f) - mean * mean;
    stats[bg * 2] = mean;
    stats[bg * 2 + 1] = rsqrtf(var + 1e-6f);
  }
}

// ---------------- group norm + transpose: x[b][c][n] -> xnT[b][n][c] bf16 ----
__global__ __launch_bounds__(256) void gn_norm_t(const float* __restrict__ x,
    const float* __restrict__ stats, const float* __restrict__ gamma,
    const float* __restrict__ beta, u16* __restrict__ xnT) {
  __shared__ u16 tile[64][72];
  int b = blockIdx.z;
  int c0 = blockIdx.y * 64, n0 = blockIdx.x * 64;
  int t = threadIdx.x;
  int cl = t >> 2, ng = (t & 3) * 16;
  int c = c0 + cl;
  float mean = stats[(b * 32 + (c >> 4)) * 2];
  float rstd = stats[(b * 32 + (c >> 4)) * 2 + 1];
  float a = gamma[c] * rstd;
  float b2 = beta[c] - mean * a;
  const float* src = x + ((size_t)b * 512 + c) * 4096 + n0 + ng;
  u16 e[16];
  #pragma unroll
  for (int q = 0; q < 4; ++q) {
    float4 v = *(const float4*)(src + q * 4);
    e[q * 4 + 0] = f2bf(v.x * a + b2);
    e[q * 4 + 1] = f2bf(v.y * a + b2);
    e[q * 4 + 2] = f2bf(v.z * a + b2);
    e[q * 4 + 3] = f2bf(v.w * a + b2);
  }
  #pragma unroll
  for (int j = 0; j < 16; ++j) tile[ng + j][cl] = e[j];
  __syncthreads();
  int nl = t >> 2, cg = (t & 3) * 16;
  uint4 w0 = *(const uint4*)&tile[nl][cg];
  uint4 w1 = *(const uint4*)&tile[nl][cg + 8];
  u16* dst = xnT + ((size_t)b * 4096 + n0 + nl) * 512 + c0 + cg;
  *(uint4*)dst = w0;
  *(uint4*)(dst + 8) = w1;
}

// ------------- bf16 NT GEMM: C[m][n] = sum_k A[m*lda+k]*B[n*ldb+k] --------
// 128x128 tile, BK=32, dbuf LDS + global_load_lds.
// EPI: 3 = fp32 out + bias[m] + resid (proj)
//      4 = fp8 out, (acc+bias[n])*scale  (qk: m=spatial, n=channel)
//      5 = fp8 out, acc+bias[m]          (v:  m=channel, n=spatial)
template<int EPI>
__global__ __launch_bounds__(256) void gemm_nt(
    const u16* __restrict__ A, const u16* __restrict__ B,
    int lda, int ldb, int K,
    const float* __restrict__ bias, const float* __restrict__ resid,
    float scale, float* __restrict__ outF, void* __restrict__ outBv, int ldo,
    size_t azs, size_t bzs, size_t ozs) {
  __shared__ __align__(16) u16 smem[16384];
  const size_t z = blockIdx.z;
  A += z * azs; B += z * bzs;
  const int t = threadIdx.x;
  const int wave = t >> 6, lane = t & 63;
  const int wm = wave >> 1, wn = wave & 1;
  const int quad = lane >> 4, li = lane & 15;
  const int m0 = blockIdx.y * 128, n0 = blockIdx.x * 128;

  const int srow = lane >> 2;
  const int scol = (lane & 3) * 8;
  const u16* gA[2];
  const u16* gB[2];
  int ldsOff[2];
  #pragma unroll
  for (int r = 0; r < 2; ++r) {
    int rb = wave + 4 * r;
    gA[r] = A + (size_t)(m0 + rb * 16 + srow) * lda + scol;
    gB[r] = B + (size_t)(n0 + rb * 16 + srow) * ldb + scol;
    ldsOff[r] = rb * 512;
  }

  f32x4 zero = {0.f, 0.f, 0.f, 0.f};
  f32x4 acc[4][4];
  #pragma unroll
  for (int i = 0; i < 4; ++i)
    #pragma unroll
    for (int j = 0; j < 4; ++j) acc[i][j] = zero;

  #pragma unroll
  for (int r = 0; r < 2; ++r) {
    gld_lds16(gA[r], &smem[ldsOff[r]]);
    gld_lds16(gB[r], &smem[8192 + ldsOff[r]]);
  }
  __syncthreads();

  for (int kt = 0; kt < K; kt += 32) {
    const int s = (kt >> 5) & 1;
    if (kt + 32 < K) {
      const int ns = s ^ 1;
      #pragma unroll
      for (int r = 0; r < 2; ++r) {
        gld_lds16(gA[r] + kt + 32, &smem[ns * 4096 + ldsOff[r]]);
        gld_lds16(gB[r] + kt + 32, &smem[8192 + ns * 4096 + ldsOff[r]]);
      }
    }
    bf16x8 af[4], bf[4];
    #pragma unroll
    for (int i = 0; i < 4; ++i) {
      af[i] = *(const bf16x8*)&smem[s * 4096 +
               (wm * 64 + i * 16 + li) * 32 + quad * 8];
      bf[i] = *(const bf16x8*)&smem[8192 + s * 4096 +
               (wn * 64 + i * 16 + li) * 32 + quad * 8];
    }
    #pragma unroll
    for (int i = 0; i < 4; ++i)
      #pragma unroll
      for (int j = 0; j < 4; ++j)
        acc[i][j] = __builtin_amdgcn_mfma_f32_16x16x32_bf16(
            af[i], bf[j], acc[i][j], 0, 0, 0);
    __syncthreads();
  }

  if (EPI == 3) {
    outF += z * ozs; resid += z * ozs;
    #pragma unroll
    for (int i = 0; i < 4; ++i)
      #pragma unroll
      for (int j = 0; j < 4; ++j) {
        int mB = m0 + wm * 64 + i * 16 + quad * 4;
        int n = n0 + wn * 64 + j * 16 + li;
        #pragma unroll
        for (int r = 0; r < 4; ++r) {
          int m = mB + r;
          float v = acc[i][j][r] + bias[m] + resid[(size_t)m * ldo + n];
          outF[(size_t)m * ldo + n] = v;
        }
      }
    return;
  }

  // fp8 outputs (EPI 4/5): bounce through LDS, coalesced stores
  u8* out8 = (u8*)outBv + z * ozs;
  u8* bnc = (u8*)smem;
  #pragma unroll
  for (int i = 0; i < 4; ++i) {
    int lm = wm * 64 + i * 16 + quad * 4;
    #pragma unroll
    for (int j = 0; j < 4; ++j) {
      int ln = wn * 64 + j * 16 + li;
      #pragma unroll
      for (int r = 0; r < 4; ++r) {
        float v = acc[i][j][r];
        u8 o;
        if (EPI == 4) o = f2f8((v + bias[n0 + ln]) * scale);
        else          o = f2f8(v + bias[m0 + lm + r]);
        bnc[(lm + r) * 144 + ln] = o;
      }
    }
  }
  __syncthreads();
  {
    int row = t >> 1, half = t & 1;
    const u8* src = &bnc[row * 144 + half * 64];
    u8* dst = out8 + (size_t)(m0 + row) * ldo + n0 + half * 64;
    #pragma unroll
    for (int cc = 0; cc < 4; ++cc)
      *(uint4*)(dst + cc * 16) = *(const uint4*)(src + cc * 16);
  }
}

// ------------- PV fp8 GEMM, 8-wave: ao = (E @ v^T) / rowsum --------------
// Waves/SIMD isolation experiment: SAME tile (128x128), SAME LDS (48KB ->
// 3 blocks/CU), SAME step count (64 x BK=64), SAME per-CU MFMA/step (384)
// as the R7 PV — but 8 waves/block => 24 waves/CU = 6 waves/SIMD (vs 3).
// Wave grid 2m x 4n, per wave 64x32 (acc[4][2], 16 MFMA/step, 2 staging
// loads/step).  __launch_bounds__(512,6) pins VGPR <= ~84.  Accumulation
// order per output element unchanged (panel0->panel1, kt ascending) ->
// bit-identical ao.
__global__ __launch_bounds__(512, 6) void pv8w(
    const u8* __restrict__ A, const u8* __restrict__ B,
    const float* __restrict__ rsum, u16* __restrict__ outp_,
    size_t azs, size_t bzs, size_t ozs) {
  // LDS: A stages s*8192 [0,24576): panel g at g*4096, region r at r*1024
  //      B stages 24576+s*8192 [24576,49152): same sub-layout.
  //      Epilogue bounce u16[128][136]=34816 overlays.
  __shared__ __align__(16) u8 smem[49152];
  const int lda = 4096, K = 4096, ldo = 512;
  const size_t z = blockIdx.z;
  A += z * azs; B += z * bzs;
  const int t = threadIdx.x;
  const int w = t >> 6, lane = t & 63;
  const int wm = w >> 2, wn = w & 3;   // wave grid 2 (M) x 4 (N)
  const int quad = lane >> 4, li = lane & 15;
  const int m0 = blockIdx.y * 128, n0 = blockIdx.x * 128;

  // staging (pre-swizzled global source, linear LDS dest):
  // wave w stages A panel (w>>2) region (w&3) and B panel (w>>2) region (w&3)
  const int us = lane ^ ((lane >> 3) & 7);
  const int srow = (us >> 1) & 31;
  const int shalf = us & 1;
  const int sg = w >> 2, sr = w & 3;
  const u8* gA = A + (size_t)(m0 + sr * 32 + srow) * lda + sg * 32 + shalf * 16;
  const u8* gB = B + (size_t)(n0 + sr * 32 + srow) * lda + sg * 32 + shalf * 16;
  const uint32_t lA = sg * 4096 + sr * 1024;
  const uint32_t lB = 24576 + sg * 4096 + sr * 1024;

  // frag read offsets within a panel: p = (2*r5+h) ^ ((r5>>2)&7)
  const int h = quad >> 1, qlo = (quad & 1) * 8;
  int aoff[4], boff[2];
  #pragma unroll
  for (int i = 0; i < 4; ++i) {
    int r5 = (i & 1) * 16 + li;
    int p = (2 * r5 + h) ^ ((r5 >> 2) & 7);
    aoff[i] = (wm * 2 + (i >> 1)) * 1024 + p * 16 + qlo;
  }
  #pragma unroll
  for (int j = 0; j < 2; ++j) {
    int r5 = j * 16 + li;
    int p = (2 * r5 + h) ^ ((r5 >> 2) & 7);
    boff[j] = wn * 1024 + p * 16 + qlo;
  }

  f32x4 zero = {0.f, 0.f, 0.f, 0.f};
  f32x4 acc[4][2];
  #pragma unroll
  for (int i = 0; i < 4; ++i)
    #pragma unroll
    for (int j = 0; j < 2; ++j) acc[i][j] = zero;

  // stage one BK=64 step: 2 glds per wave (1 A + 1 B)
  auto STAGE = [&](int kt, int st) {
    gld_lds16(gA + kt, &smem[st * 8192 + lA]);
    gld_lds16(gB + kt, &smem[st * 8192 + lB]);
  };

  STAGE(0, 0);
  STAGE(64, 1);
  __builtin_amdgcn_sched_barrier(0);
  asm volatile("s_waitcnt vmcnt(2)");
  bar();

  int s = 0;
  for (int kt = 0; kt < K; kt += 64) {
    if (kt + 128 < K) STAGE(kt + 128, (s == 0) ? 2 : s - 1);
    const int sb = s * 8192;
    long af[4][2], bf[2][2];
    #pragma unroll
    for (int i = 0; i < 4; ++i)
      #pragma unroll
      for (int g = 0; g < 2; ++g)
        af[i][g] = *(const long*)&smem[sb + g * 4096 + aoff[i]];
    #pragma unroll
    for (int j = 0; j < 2; ++j)
      #pragma unroll
      for (int g = 0; g < 2; ++g)
        bf[j][g] = *(const long*)&smem[24576 + sb + g * 4096 + boff[j]];
    #pragma unroll
    for (int i = 0; i < 4; ++i)
      #pragma unroll
      for (int j = 0; j < 2; ++j) {
        acc[i][j] = __builtin_amdgcn_mfma_f32_16x16x32_fp8_fp8(
            af[i][0], bf[j][0], acc[i][j], 0, 0, 0);
        acc[i][j] = __builtin_amdgcn_mfma_f32_16x16x32_fp8_fp8(
            af[i][1], bf[j][1], acc[i][j], 0, 0, 0);
      }
    if (kt + 64 < K) {
      __builtin_amdgcn_sched_barrier(0);
      if (kt + 128 < K) asm volatile("s_waitcnt vmcnt(2)");
      else              asm volatile("s_waitcnt vmcnt(0)");
      bar();
    }
    s = (s == 2) ? 0 : s + 1;
  }
  __syncthreads();  // all waves done reading stages before bounce overlay

  {  // epilogue: scale by rcp(rowsum), bf16 bounce + coalesced stores
    const float* rsF = rsum + z * 4096;
    u16* outp = outp_ + z * ozs;
    u16* b16 = (u16*)smem;
    #pragma unroll
    for (int i = 0; i < 4; ++i) {
      int lm = wm * 64 + i * 16 + quad * 4;
      float rinv[4];
      #pragma unroll
      for (int r = 0; r < 4; ++r)
        rinv[r] = __builtin_amdgcn_rcpf(rsF[m0 + lm + r]);
      #pragma unroll
      for (int j = 0; j < 2; ++j) {
        int ln = wn * 32 + j * 16 + li;
        #pragma unroll
        for (int r = 0; r < 4; ++r)
          b16[(lm + r) * 136 + ln] = f2bf(acc[i][j][r] * rinv[r]);
      }
    }
    __syncthreads();
    int row = t >> 2, q = t & 3;  // 512 threads: 128 rows x 4 quarters
    const u16* src = &b16[row * 136 + q * 32];
    u16* dst = outp + (size_t)(m0 + row) * ldo + n0 + q * 32;
    #pragma unroll
    for (int cc = 0; cc < 4; ++cc)
      *(uint4*)(dst + cc * 8) = *(const uint4*)(src + cc * 8);
  }
}

// ------------- QK^T 256x128-tile, 8-wave fp8 GEMM + exp + rowsum ----------
// R10-proven: 122 -> ~100 us (waves/SIMD 3->4, per-CU MFMA/step 384->512).
__global__ __launch_bounds__(512, 4) void qk8w(
    const u8* __restrict__ A, const u8* __restrict__ B,
    float* __restrict__ rowsum, u8* __restrict__ outE) {
  // LDS: A stages s*16384 [0,49152): panel g at g*8192, region w (0..7)*1024
  //      B stages 49152+s*8192 [49152,73728): panel g at g*4096, region
  //      (w&3)*1024.  Epilogue bounce u8[256][144]=36864 overlays [0,..).
  __shared__ __align__(16) u8 smem[73728];
  const int lda = 1024, K = 512;
  const size_t z = blockIdx.z;
  A += (size_t)z * 4096 * 1024;
  B += (size_t)z * 4096 * 1024;
  float* rsF = rowsum + (size_t)z * 4096;
  u8* outp = outE + (size_t)z * 4096 * 4096;

  const int t = threadIdx.x;
  const int w = t >> 6, lane = t & 63;
  const int wm = w >> 1, wn = w & 1;   // wave grid 4 (M) x 2 (N)
  const int quad = lane >> 4, li = lane & 15;
  const int m0 = blockIdx.y * 256, n0 = blockIdx.x * 128;

  // staging (pre-swizzled global source, linear LDS dest)
  const int us = lane ^ ((lane >> 3) & 7);
  const int srow = (us >> 1) & 31;
  const int shalf = us & 1;
  const u8* gA = A + (size_t)(m0 + w * 32 + srow) * lda + shalf * 16;
  const bool doB = w < 4;
  const u8* gB = B + (size_t)(n0 + (w & 3) * 32 + srow) * lda + shalf * 16;

  // frag read offsets: p = (2*r5+h) ^ ((r5>>2)&7) within a 1KB region
  const int h = quad >> 1, qlo = (quad & 1) * 8;
  int aoff[4], boff[4];
  #pragma unroll
  for (int i = 0; i < 4; ++i) {
    int r5 = (i & 1) * 16 + li;
    int p = (2 * r5 + h) ^ ((r5 >> 2) & 7);
    aoff[i] = (wm * 2 + (i >> 1)) * 1024 + p * 16 + qlo;
    boff[i] = (wn * 2 + (i >> 1)) * 1024 + p * 16 + qlo;
  }

  f32x4 zero = {0.f, 0.f, 0.f, 0.f};
  f32x4 acc[4][4];
  #pragma unroll
  for (int i = 0; i < 4; ++i)
    #pragma unroll
    for (int j = 0; j < 4; ++j) acc[i][j] = zero;

  // stage one BK=64 step (A: 2 glds all waves; B: 2 glds waves 0-3)
  auto STAGE = [&](int kt, int st) {
    int sA = st * 16384, sB = 49152 + st * 8192;
    #pragma unroll
    for (int g = 0; g < 2; ++g) {
      gld_lds16(gA + kt + g * 32, &smem[sA + g * 8192 + w * 1024]);
      if (doB)
        gld_lds16(gB + kt + g * 32, &smem[sB + g * 4096 + (w & 3) * 1024]);
    }
  };

  STAGE(0, 0);
  STAGE(64, 1);
  __builtin_amdgcn_sched_barrier(0);
  if (doB) asm volatile("s_waitcnt vmcnt(4)");
  else     asm volatile("s_waitcnt vmcnt(2)");
  bar();

  int s = 0;
  for (int kt = 0; kt < K; kt += 64) {
    if (kt + 128 < K) STAGE(kt + 128, (s == 0) ? 2 : s - 1);
    const int sA = s * 16384, sB = 49152 + s * 8192;
    long af[4][2], bf[4][2];
    #pragma unroll
    for (int i = 0; i < 4; ++i) {
      #pragma unroll
      for (int g = 0; g < 2; ++g) {
        af[i][g] = *(const long*)&smem[sA + g * 8192 + aoff[i]];
        bf[i][g] = *(const long*)&smem[sB + g * 4096 + boff[i]];
      }
    }
    #pragma unroll
    for (int i = 0; i < 4; ++i)
      #pragma unroll
      for (int j = 0; j < 4; ++j) {
        acc[i][j] = __builtin_amdgcn_mfma_f32_16x16x32_fp8_fp8(
            af[i][0], bf[j][0], acc[i][j], 0, 0, 0);
        acc[i][j] = __builtin_amdgcn_mfma_f32_16x16x32_fp8_fp8(
            af[i][1], bf[j][1], acc[i][j], 0, 0, 0);
      }
    if (kt + 64 < K) {
      __builtin_amdgcn_sched_barrier(0);
      if (kt + 128 < K) {
        if (doB) asm volatile("s_waitcnt vmcnt(4)");
        else     asm volatile("s_waitcnt vmcnt(2)");
      } else {
        asm volatile("s_waitcnt vmcnt(0)");
      }
      bar();
    }
    s = (s == 2) ? 0 : s + 1;
  }
  __syncthreads();  // all waves done reading stages before bounce overlay

  // epilogue: exp + clamp, rowsum atomics, fp8 bounce + coalesced stores
  #pragma unroll
  for (int i = 0; i < 4; ++i) {
    int lm = wm * 64 + i * 16 + quad * 4;   // rows 0..255
    float rs[4] = {0.f, 0.f, 0.f, 0.f};
    #pragma unroll
    for (int j = 0; j < 4; ++j) {
      int ln = wn * 64 + j * 16 + li;       // cols 0..127
      #pragma unroll
      for (int r = 0; r < 4; ++r) {
        float e = fminf(__expf(acc[i][j][r]), 448.f);
        smem[(lm + r) * 144 + ln] = f2f8(e);
        rs[r] += e;
      }
    }
    #pragma unroll
    for (int r = 0; r < 4; ++r) {
      rs[r] += __shfl_xor(rs[r], 1);
      rs[r] += __shfl_xor(rs[r], 2);
      rs[r] += __shfl_xor(rs[r], 4);
      rs[r] += __shfl_xor(rs[r], 8);
    }
    if (li == 0) {
      #pragma unroll
      for (int r = 0; r < 4; ++r) atomicAdd(&rsF[m0 + lm + r], rs[r]);
    }
  }
  __syncthreads();
  {
    int row = t >> 1, half = t & 1;   // 512 threads: 256 rows x 2 halves
    const u8* src = &smem[row * 144 + half * 64];
    u8* dst = outp + (size_t)(m0 + row) * 4096 + n0 + half * 64;
    #pragma unroll
    for (int cc = 0; cc < 4; ++cc)
      *(uint4*)(dst + cc * 16) = *(const uint4*)(src + cc * 16);
  }
}

extern "C" void kernel_launch(void* const* d_in, const int* in_sizes, int n_in,
                              void* d_out, int out_size, void* d_ws, size_t ws_size,
                              hipStream_t stream) {
  (void)in_sizes; (void)n_in; (void)out_size; (void)ws_size;
  const float* x      = (const float*)d_in[0];
  const float* gamma  = (const float*)d_in[1];
  const float* beta   = (const float*)d_in[2];
  const float* w_qkv  = (const float*)d_in[3];
  const float* b_qkv  = (const float*)d_in[4];
  const float* w_proj = (const float*)d_in[5];
  const float* b_proj = (const float*)d_in[6];
  float* out = (float*)d_out;

  const int C = 512, N = 4096;
  const size_t NC = (size_t)N * C;
  const float scale = 0.21022410381342863f;  // 512^-0.25

  char* ws = (char*)d_ws;
  size_t off = 0;
  auto alloc = [&](size_t bytes) -> char* {
    char* p = ws + off; off += (bytes + 255) & ~(size_t)255; return p;
  };
  u16*   wq_bf  = (u16*)alloc((size_t)1536 * 512 * 2);
  u16*   wp_bf  = (u16*)alloc((size_t)512 * 512 * 2);
  float* stats  = (float*)alloc(128 * 2 * 4);
  float* rowsum = (float*)alloc((size_t)4 * N * 4);
  u16*   xnT    = (u16*)alloc((size_t)4 * NC * 2);      // [b][n][c] bf16
  u8*    qkT    = (u8*)alloc((size_t)4 * N * 1024);     // [b][i][o] fp8, o<1024
  u8*    vbf    = (u8*)alloc((size_t)4 * 512 * 4096);   // [b][c][j] fp8
  u16*   ao     = (u16*)alloc((size_t)4 * NC * 2);      // [b][i][c] bf16
  u8*    E      = (u8*)alloc((size_t)4 * N * N);        // [b][i][j] fp8

  cvt_weights<<<3072, 256, 0, stream>>>(w_qkv, w_proj, wq_bf, wp_bf);
  gn_stats<<<128, 256, 0, stream>>>(x, stats);
  gn_norm_t<<<dim3(64, 8, 4), 256, 0, stream>>>(x, stats, gamma, beta, xnT);
  hipMemsetAsync(rowsum, 0, (size_t)4 * N * 4, stream);

  // qkT[b][i][o] = fp8((sum_c xnT[b][i][c]*wq[o][c] + b_qkv[o]) * scale)
  gemm_nt<4><<<dim3(8, 32, 4), 256, 0, stream>>>(
      xnT, wq_bf, 512, 512, 512, b_qkv, nullptr, scale,
      nullptr, qkT, 1024, NC, 0, (size_t)N * 1024);
  // vbf[b][c][j] = fp8(sum_k wq[1024+c][k]*xnT[b][j][k] + b_qkv[1024+c])
  gemm_nt<5><<<dim3(32, 4, 4), 256, 0, stream>>>(
      wq_bf + (size_t)1024 * 512, xnT, 512, 512, 512, b_qkv + 1024, nullptr,
      0.f, nullptr, vbf, 4096, 0, NC, (size_t)512 * 4096);
  // E[b][i][j] = fp8(exp(S)), rowsum[b][i] += partials (256x128, 8 waves)
  qk8w<<<dim3(32, 16, 4), 512, 0, stream>>>(qkT, qkT + 512, rowsum, E);
  // ao[b][i][c] = bf16((sum_j E*v) * rcp(rowsum[b][i]))  (8-wave, 6 w/SIMD)
  pv8w<<<dim3(4, 32, 4), 512, 0, stream>>>(
      E, vbf, rowsum, ao, (size_t)N * N, (size_t)512 * 4096, NC);
  // out[b][o][n] = sum_c wp[o][c]*ao[b][n][c] + b_proj[o] + x[b][o][n]
  gemm_nt<3><<<dim3(32, 4, 4), 256, 0, stream>>>(
      wp_bf, ao, 512, 512, 512, b_proj, x, 0.f,
      out, nullptr, 4096, 0, NC, NC);
}